// Round 1
// baseline (2279.763 us; speedup 1.0000x reference)
//
#include <hip/hip_runtime.h>
#include <hip/hip_bf16.h>
#include <math.h>
#include <stdint.h>

// Problem constants
#define S_LEN 2048
#define NH    32
#define NKV   8
#define HD    128
#define HIDD  4096

typedef unsigned short u16;
typedef __attribute__((ext_vector_type(8))) short bf16x8;
typedef __attribute__((ext_vector_type(4))) float f32x4;

// ---------- helpers ----------

// scale = max(absmax, 1e-5) / 127  (exact f32 division, matches jnp)
__device__ __forceinline__ float slot_scale(const unsigned* slot) {
    return fmaxf(__uint_as_float(*slot), 1e-5f) / 127.0f;
}

// quantized integer (as float) -> bf16 bits. Values are integers in [-128,127],
// whose f32 representation has zero low 16 bits -> truncation is exact.
__device__ __forceinline__ u16 qbits(float x, float s) {
    float q = rintf(x / s);
    q = fminf(fmaxf(q, -128.0f), 127.0f);
    return (u16)(__float_as_uint(q) >> 16);
}

__device__ __forceinline__ void wave_amax_atomic(float m, unsigned* slot, int lane) {
    #pragma unroll
    for (int o = 32; o; o >>= 1) m = fmaxf(m, __shfl_xor(m, o));
    if (lane == 0) atomicMax(slot, __float_as_uint(m));
}

// ---------- absmax over f32 tensor (n divisible by 4) ----------
__global__ __launch_bounds__(256) void absmax_kernel(const float* __restrict__ x,
                                                     size_t n4, unsigned* slot) {
    size_t i = (size_t)blockIdx.x * blockDim.x + threadIdx.x;
    size_t stride = (size_t)gridDim.x * blockDim.x;
    const float4* x4 = (const float4*)x;
    float m = 0.0f;
    for (; i < n4; i += stride) {
        float4 v = x4[i];
        m = fmaxf(m, fmaxf(fmaxf(fabsf(v.x), fabsf(v.y)), fmaxf(fabsf(v.z), fabsf(v.w))));
    }
    wave_amax_atomic(m, slot, threadIdx.x & 63);
}

// ---------- quantize f32 -> bf16-int (same layout) ----------
__global__ __launch_bounds__(256) void quant_kernel(const float* __restrict__ x,
                                                    size_t n4, const unsigned* slot,
                                                    u16* __restrict__ out) {
    float s = slot_scale(slot);
    size_t i = (size_t)blockIdx.x * blockDim.x + threadIdx.x;
    size_t stride = (size_t)gridDim.x * blockDim.x;
    const float4* x4 = (const float4*)x;
    ushort4* o4 = (ushort4*)out;
    for (; i < n4; i += stride) {
        float4 v = x4[i];
        ushort4 o;
        o.x = qbits(v.x, s); o.y = qbits(v.y, s);
        o.z = qbits(v.z, s); o.w = qbits(v.w, s);
        o4[i] = o;
    }
}

// ---------- GEMM: C[M,N] = (A_int @ B_int^T) * sA*sB ; A:(M,K) B:(N,K) bf16-ints ----------
__global__ __launch_bounds__(256) void gemm_bt_kernel(const u16* __restrict__ A,
                                                      const u16* __restrict__ B,
                                                      float* __restrict__ C,
                                                      int M, int N, int K,
                                                      const unsigned* __restrict__ sA_slot,
                                                      const unsigned* __restrict__ sB_slot,
                                                      unsigned* out_amax) {
    __shared__ __align__(16) u16 Asm[128 * 64];
    __shared__ __align__(16) u16 Bsm[128 * 64];
    const int tid  = threadIdx.x;
    const int lane = tid & 63;
    const int wave = tid >> 6;
    const int m0 = blockIdx.x * 128;
    const int n0 = blockIdx.y * 128;
    const int wr = (wave >> 1) * 64;
    const int wc = (wave & 1) * 64;
    const int l15 = lane & 15;
    const int l4  = lane >> 4;

    f32x4 zero4 = {0.f, 0.f, 0.f, 0.f};
    f32x4 acc[4][4];
    #pragma unroll
    for (int i = 0; i < 4; ++i)
        #pragma unroll
        for (int j = 0; j < 4; ++j) acc[i][j] = zero4;

    for (int k0 = 0; k0 < K; k0 += 64) {
        __syncthreads();
        #pragma unroll
        for (int c = 0; c < 4; ++c) {
            int cid = c * 256 + tid;          // 1024 chunks of 8 elements
            int row = cid >> 3;
            int col = (cid & 7) << 3;
            *(bf16x8*)&Asm[row * 64 + col] =
                *(const bf16x8*)&A[(size_t)(m0 + row) * K + k0 + col];
            *(bf16x8*)&Bsm[row * 64 + col] =
                *(const bf16x8*)&B[(size_t)(n0 + row) * K + k0 + col];
        }
        __syncthreads();
        #pragma unroll
        for (int kk = 0; kk < 2; ++kk) {
            bf16x8 af[4], bfr[4];
            #pragma unroll
            for (int i = 0; i < 4; ++i)
                af[i] = *(const bf16x8*)&Asm[(wr + i * 16 + l15) * 64 + kk * 32 + l4 * 8];
            #pragma unroll
            for (int j = 0; j < 4; ++j)
                bfr[j] = *(const bf16x8*)&Bsm[(wc + j * 16 + l15) * 64 + kk * 32 + l4 * 8];
            #pragma unroll
            for (int i = 0; i < 4; ++i)
                #pragma unroll
                for (int j = 0; j < 4; ++j)
                    acc[i][j] = __builtin_amdgcn_mfma_f32_16x16x32_bf16(af[i], bfr[j], acc[i][j], 0, 0, 0);
        }
    }

    float scale = slot_scale(sA_slot) * slot_scale(sB_slot);
    float lm = 0.0f;
    #pragma unroll
    for (int i = 0; i < 4; ++i)
        #pragma unroll
        for (int j = 0; j < 4; ++j)
            #pragma unroll
            for (int r = 0; r < 4; ++r) {
                int row = m0 + wr + i * 16 + l4 * 4 + r;
                int col = n0 + wc + j * 16 + l15;
                float v = acc[i][j][r] * scale;
                C[(size_t)row * N + col] = v;
                lm = fmaxf(lm, fabsf(v));
            }
    if (out_amax) wave_amax_atomic(lm, out_amax, lane);
}

// ---------- RMSNorm + RoPE in-place on (S, nh*128) f32, + absmax ----------
__global__ __launch_bounds__(256) void rmsrope_kernel(float* __restrict__ x,
                                                      const float* __restrict__ cosb,
                                                      const float* __restrict__ sinb,
                                                      const float* __restrict__ w,
                                                      int nh, unsigned* amax_slot) {
    int row  = blockIdx.x * 4 + (threadIdx.x >> 6);   // one wave per (s,h) row
    int lane = threadIdx.x & 63;
    int s = row / nh;
    float* xr = x + (size_t)row * 128;
    float a = xr[lane], b = xr[lane + 64];
    float ss = a * a + b * b;
    #pragma unroll
    for (int o = 32; o; o >>= 1) ss += __shfl_xor(ss, o);
    float inv = 1.0f / sqrtf(ss * (1.0f / 128.0f) + 1e-5f);
    float ya = (a * inv) * w[lane];
    float yb = (b * inv) * w[lane + 64];
    const float* cr = cosb + (size_t)s * 128;
    const float* sr = sinb + (size_t)s * 128;
    float o0 = ya * cr[lane]      - yb * sr[lane];        // rotate_half: -x[d+64]
    float o1 = yb * cr[lane + 64] + ya * sr[lane + 64];   //              +x[d-64]
    xr[lane] = o0;
    xr[lane + 64] = o1;
    wave_amax_atomic(fmaxf(fabsf(o0), fabsf(o1)), amax_slot, lane);
}

// ---------- quantize + reorder (S, nh, D) -> (nh, S, D) bf16-ints ----------
__global__ __launch_bounds__(256) void quant_qk_kernel(const float* __restrict__ x,
                                                       int nh, const unsigned* slot,
                                                       u16* __restrict__ out) {
    int tid = blockIdx.x * blockDim.x + threadIdx.x;
    float s = slot_scale(slot);
    int d  = tid & 127;
    int h  = (tid >> 7) % nh;
    int sp = tid / (128 * nh);
    out[((size_t)h * S_LEN + sp) * 128 + d] = qbits(x[tid], s);
}

// ---------- quantize + transpose V: (S, KV, D) -> (KV, D, S) bf16-ints ----------
__global__ __launch_bounds__(256) void quant_v_kernel(const float* __restrict__ x,
                                                      const unsigned* slot,
                                                      u16* __restrict__ out) {
    int tid = blockIdx.x * blockDim.x + threadIdx.x;
    float s = slot_scale(slot);
    int d  = tid & 127;
    int kv = (tid >> 7) & 7;
    int sp = tid >> 10;
    out[((size_t)kv * 128 + d) * S_LEN + sp] = qbits(x[tid], s);
}

// ---------- attention: two-pass flash with quantized P ----------
// Qq:(NH,S,D) Kq:(NKV,S,D) Vt:(NKV,D,S) all bf16-ints. O:(S,NH*D) f32.
__global__ __launch_bounds__(256) void attn_kernel(const u16* __restrict__ Qq,
                                                   const u16* __restrict__ Kq,
                                                   const u16* __restrict__ Vt,
                                                   const unsigned* sq_slot,
                                                   const unsigned* sk_slot,
                                                   const unsigned* sv_slot,
                                                   float* __restrict__ O,
                                                   unsigned* amax_slot) {
    __shared__ __align__(16) u16 Klds[32 * 128];
    __shared__ __align__(16) u16 Vlds[128 * 32];
    __shared__ __align__(16) u16 plds[4][16 * 32];

    const int tid  = threadIdx.x;
    const int lane = tid & 63;
    const int wave = tid >> 6;
    const int qb = blockIdx.x;
    const int h  = blockIdx.y;
    const int kv = h >> 2;                  // n_rep = 4
    const int qr0 = qb * 64 + wave * 16;
    const int l15 = lane & 15;
    const int l4  = lane >> 4;

    const float sq = slot_scale(sq_slot);
    const float sk = slot_scale(sk_slot);
    const float sv = slot_scale(sv_slot);
    const float qk_scale = sq * sk * 0.08838834764831845f;  // D^-0.5
    const float SP = 1.0f / 127.0f;                          // max(p) == 1.0 exactly

    // Q fragments (held in regs for both passes)
    bf16x8 qf[4];
    {
        const u16* qp = Qq + ((size_t)h * S_LEN + qr0 + l15) * 128 + l4 * 8;
        #pragma unroll
        for (int ks = 0; ks < 4; ++ks) qf[ks] = *(const bf16x8*)(qp + ks * 32);
    }

    const int kb_last = qb * 4 + wave;         // last (diagonal) 16-block for this wave
    const int kc_max  = (qb * 4 + 3) >> 1;     // uniform 32-chunk bound for whole block

    float mrow[4], lrow[4];
    #pragma unroll
    for (int r = 0; r < 4; ++r) { mrow[r] = -__builtin_inff(); lrow[r] = 0.0f; }

    // ---- pass 1: row max m and row sum l ----
    for (int kc = 0; kc <= kc_max; ++kc) {
        __syncthreads();
        #pragma unroll
        for (int i = 0; i < 2; ++i) {   // stage K tile 32x128
            int idx = i * 256 + tid;
            int row = idx >> 4, col = (idx & 15) << 3;
            *(bf16x8*)&Klds[row * 128 + col] =
                *(const bf16x8*)&Kq[((size_t)kv * S_LEN + kc * 32 + row) * 128 + col];
        }
        __syncthreads();
        #pragma unroll
        for (int half = 0; half < 2; ++half) {
            int kb = kc * 2 + half;
            if (kb > kb_last) continue;
            f32x4 sacc = {0.f, 0.f, 0.f, 0.f};
            #pragma unroll
            for (int ks = 0; ks < 4; ++ks) {
                bf16x8 kf = *(const bf16x8*)&Klds[(half * 16 + l15) * 128 + ks * 32 + l4 * 8];
                sacc = __builtin_amdgcn_mfma_f32_16x16x32_bf16(qf[ks], kf, sacc, 0, 0, 0);
            }
            bool diag = (kb == kb_last);
            int kpos = kb * 16 + l15;
            #pragma unroll
            for (int r = 0; r < 4; ++r) {
                float sc = sacc[r] * qk_scale;
                int qrow = qr0 + l4 * 4 + r;
                if (diag && kpos > qrow) sc = -__builtin_inff();
                float tm = sc;
                tm = fmaxf(tm, __shfl_xor(tm, 1));
                tm = fmaxf(tm, __shfl_xor(tm, 2));
                tm = fmaxf(tm, __shfl_xor(tm, 4));
                tm = fmaxf(tm, __shfl_xor(tm, 8));
                float mn = fmaxf(mrow[r], tm);
                float p = expf(sc - mn);       // masked: expf(-inf)=0
                float ts = p;
                ts += __shfl_xor(ts, 1);
                ts += __shfl_xor(ts, 2);
                ts += __shfl_xor(ts, 4);
                ts += __shfl_xor(ts, 8);
                lrow[r] = lrow[r] * expf(mrow[r] - mn) + ts;
                mrow[r] = mn;
            }
        }
    }

    // ---- pass 2: quantized P @ V ----
    f32x4 oacc[8];
    {
        f32x4 zero4 = {0.f, 0.f, 0.f, 0.f};
        #pragma unroll
        for (int dt = 0; dt < 8; ++dt) oacc[dt] = zero4;
    }
    for (int kc = 0; kc <= kc_max; ++kc) {
        __syncthreads();
        #pragma unroll
        for (int i = 0; i < 2; ++i) {   // stage K (32x128) and V^T (128x32) tiles
            int idx = i * 256 + tid;
            int krow = idx >> 4, kcol = (idx & 15) << 3;
            *(bf16x8*)&Klds[krow * 128 + kcol] =
                *(const bf16x8*)&Kq[((size_t)kv * S_LEN + kc * 32 + krow) * 128 + kcol];
            int vrow = idx >> 2, vcol = (idx & 3) << 3;
            *(bf16x8*)&Vlds[vrow * 32 + vcol] =
                *(const bf16x8*)&Vt[((size_t)kv * 128 + vrow) * S_LEN + kc * 32 + vcol];
        }
        __syncthreads();
        #pragma unroll
        for (int half = 0; half < 2; ++half) {
            int kb = kc * 2 + half;
            u16 pz[4];
            if (kb <= kb_last) {
                f32x4 sacc = {0.f, 0.f, 0.f, 0.f};
                #pragma unroll
                for (int ks = 0; ks < 4; ++ks) {
                    bf16x8 kf = *(const bf16x8*)&Klds[(half * 16 + l15) * 128 + ks * 32 + l4 * 8];
                    sacc = __builtin_amdgcn_mfma_f32_16x16x32_bf16(qf[ks], kf, sacc, 0, 0, 0);
                }
                bool diag = (kb == kb_last);
                int kpos = kb * 16 + l15;
                #pragma unroll
                for (int r = 0; r < 4; ++r) {
                    float sc = sacc[r] * qk_scale;
                    int qrow = qr0 + l4 * 4 + r;
                    if (diag && kpos > qrow) sc = -__builtin_inff();
                    float p = expf(sc - mrow[r]) / lrow[r];
                    float q = rintf(p / SP);   // p<=1 -> no clip needed
                    pz[r] = (u16)(__float_as_uint(q) >> 16);
                }
            } else {
                #pragma unroll
                for (int r = 0; r < 4; ++r) pz[r] = 0;
            }
            #pragma unroll
            for (int r = 0; r < 4; ++r)
                plds[wave][(l4 * 4 + r) * 32 + half * 16 + l15] = pz[r];
        }
        __syncthreads();   // order plds writes (cross-lane) before fragment reads
        bf16x8 pf = *(const bf16x8*)&plds[wave][l15 * 32 + l4 * 8];
        #pragma unroll
        for (int dt = 0; dt < 8; ++dt) {
            bf16x8 vf = *(const bf16x8*)&Vlds[(dt * 16 + l15) * 32 + l4 * 8];
            oacc[dt] = __builtin_amdgcn_mfma_f32_16x16x32_bf16(pf, vf, oacc[dt], 0, 0, 0);
        }
    }

    // epilogue: dequant (s_p * s_v), write O, absmax
    float osc = SP * sv;
    float lm = 0.0f;
    #pragma unroll
    for (int dt = 0; dt < 8; ++dt)
        #pragma unroll
        for (int r = 0; r < 4; ++r) {
            int qrow = qr0 + l4 * 4 + r;
            int col = h * 128 + dt * 16 + l15;
            float v = oacc[dt][r] * osc;
            O[(size_t)qrow * (NH * 128) + col] = v;
            lm = fmaxf(lm, fabsf(v));
        }
    wave_amax_atomic(lm, amax_slot, lane);
}

// ---------- host ----------
extern "C" void kernel_launch(void* const* d_in, const int* in_sizes, int n_in,
                              void* d_out, int out_size, void* d_ws, size_t ws_size,
                              hipStream_t stream) {
    const float* hs   = (const float*)d_in[0];
    const float* cosb = (const float*)d_in[1];
    const float* sinb = (const float*)d_in[2];
    // d_in[3] attention_mask: causal, implemented analytically
    const float* Wq   = (const float*)d_in[4];
    const float* Wk   = (const float*)d_in[5];
    const float* Wv   = (const float*)d_in[6];
    const float* Wo   = (const float*)d_in[7];
    const float* qnw  = (const float*)d_in[8];
    const float* knw  = (const float*)d_in[9];
    float* out = (float*)d_out;

    char* ws = (char*)d_ws;
    unsigned* slots = (unsigned*)ws;
    // slots: 0 hs, 1 Wq, 2 Wk, 3 Wv, 4 Wo, 5 q, 6 k, 7 v, 8 attn
    size_t off = 256;
    auto take = [&](size_t bytes) { size_t o = off; off += (bytes + 255) & ~(size_t)255; return o; };
    u16*   hsq  = (u16*)(ws + take((size_t)S_LEN * HIDD * 2));       // 16 MB
    u16*   Wqq  = (u16*)(ws + take((size_t)NH * HD * HIDD * 2));     // 32 MB
    u16*   Wkq  = (u16*)(ws + take((size_t)NKV * HD * HIDD * 2));    //  8 MB
    u16*   Wvq  = (u16*)(ws + take((size_t)NKV * HD * HIDD * 2));    //  8 MB
    u16*   Woq  = (u16*)(ws + take((size_t)HIDD * NH * HD * 2));     // 32 MB
    float* qf   = (float*)(ws + take((size_t)S_LEN * NH * HD * 4));  // 32 MB (reused as attn out)
    float* kf   = (float*)(ws + take((size_t)S_LEN * NKV * HD * 4)); //  8 MB
    float* vf   = (float*)(ws + take((size_t)S_LEN * NKV * HD * 4)); //  8 MB
    u16*   qq   = (u16*)(ws + take((size_t)NH * S_LEN * HD * 2));    // 16 MB
    u16*   kq   = (u16*)(ws + take((size_t)NKV * S_LEN * HD * 2));   //  4 MB
    u16*   vtq  = (u16*)(ws + take((size_t)NKV * HD * S_LEN * 2));   //  4 MB
    float* attnf = qf;     // q f32 dead after quant_qk
    u16*   attnq = hsq;    // hs_q dead after the three projections

    hipMemsetAsync(ws, 0, 64, stream);

    const size_t n_hs = (size_t)S_LEN * HIDD;
    const size_t n_wq = (size_t)NH * HD * HIDD;
    const size_t n_wk = (size_t)NKV * HD * HIDD;

    absmax_kernel<<<1024, 256, 0, stream>>>(hs, n_hs / 4, slots + 0);
    absmax_kernel<<<1024, 256, 0, stream>>>(Wq, n_wq / 4, slots + 1);
    absmax_kernel<<<512,  256, 0, stream>>>(Wk, n_wk / 4, slots + 2);
    absmax_kernel<<<512,  256, 0, stream>>>(Wv, n_wk / 4, slots + 3);
    absmax_kernel<<<1024, 256, 0, stream>>>(Wo, n_wq / 4, slots + 4);

    quant_kernel<<<2048, 256, 0, stream>>>(hs, n_hs / 4, slots + 0, hsq);
    quant_kernel<<<2048, 256, 0, stream>>>(Wq, n_wq / 4, slots + 1, Wqq);
    quant_kernel<<<1024, 256, 0, stream>>>(Wk, n_wk / 4, slots + 2, Wkq);
    quant_kernel<<<1024, 256, 0, stream>>>(Wv, n_wk / 4, slots + 3, Wvq);
    quant_kernel<<<2048, 256, 0, stream>>>(Wo, n_wq / 4, slots + 4, Woq);

    dim3 gq(S_LEN / 128, (NH * HD) / 128);    // (16, 32)
    dim3 gk(S_LEN / 128, (NKV * HD) / 128);   // (16, 8)
    gemm_bt_kernel<<<gq, 256, 0, stream>>>(hsq, Wqq, qf, S_LEN, NH * HD, HIDD,
                                           slots + 0, slots + 1, nullptr);
    gemm_bt_kernel<<<gk, 256, 0, stream>>>(hsq, Wkq, kf, S_LEN, NKV * HD, HIDD,
                                           slots + 0, slots + 2, nullptr);
    gemm_bt_kernel<<<gk, 256, 0, stream>>>(hsq, Wvq, vf, S_LEN, NKV * HD, HIDD,
                                           slots + 0, slots + 3, slots + 7);

    rmsrope_kernel<<<(S_LEN * NH) / 4, 256, 0, stream>>>(qf, cosb, sinb, qnw, NH, slots + 5);
    rmsrope_kernel<<<(S_LEN * NKV) / 4, 256, 0, stream>>>(kf, cosb, sinb, knw, NKV, slots + 6);

    quant_qk_kernel<<<(int)((size_t)S_LEN * NH * HD / 256), 256, 0, stream>>>(qf, NH, slots + 5, qq);
    quant_qk_kernel<<<(int)((size_t)S_LEN * NKV * HD / 256), 256, 0, stream>>>(kf, NKV, slots + 6, kq);
    quant_v_kernel<<<(int)((size_t)S_LEN * NKV * HD / 256), 256, 0, stream>>>(vf, slots + 7, vtq);

    attn_kernel<<<dim3(S_LEN / 64, NH), 256, 0, stream>>>(qq, kq, vtq,
                                                          slots + 5, slots + 6, slots + 7,
                                                          attnf, slots + 8);

    quant_kernel<<<2048, 256, 0, stream>>>(attnf, n_hs / 4, slots + 8, attnq);
    gemm_bt_kernel<<<gq, 256, 0, stream>>>(attnq, Woq, out, S_LEN, NH * HD, HIDD,
                                           slots + 8, slots + 4, nullptr);
    (void)in_sizes; (void)n_in; (void)out_size; (void)ws_size;
}

// Round 2
// 1231.020 us; speedup vs baseline: 1.8519x; 1.8519x over previous
//
#include <hip/hip_runtime.h>
#include <hip/hip_bf16.h>
#include <math.h>
#include <stdint.h>

// Problem constants
#define S_LEN 2048
#define NH    32
#define NKV   8
#define HD    128
#define HIDD  4096

typedef unsigned short u16;
typedef __attribute__((ext_vector_type(8))) short bf16x8;
typedef __attribute__((ext_vector_type(4))) float f32x4;

// ---------- helpers ----------

// scale = max(absmax, 1e-5) / 127  (exact f32 division, matches jnp)
__device__ __forceinline__ float slot_scale(const unsigned* slot) {
    return fmaxf(__uint_as_float(*slot), 1e-5f) / 127.0f;
}

// quantized integer (as float) -> bf16 bits. Values are integers in [-128,127],
// whose f32 representation has zero low 16 bits -> truncation is exact.
__device__ __forceinline__ u16 qbits(float x, float s) {
    float q = rintf(x / s);
    q = fminf(fmaxf(q, -128.0f), 127.0f);
    return (u16)(__float_as_uint(q) >> 16);
}

// block-level absmax -> ONE atomic per block (same-address atomics serialize
// at ~11ns each through L2; per-wave atomics were 65536-deep = 720us)
__device__ __forceinline__ void block_amax_atomic(float m, unsigned* slot) {
    __shared__ float wmax[8];
    const int lane = threadIdx.x & 63;
    const int wid  = threadIdx.x >> 6;
    const int nw   = blockDim.x >> 6;
    #pragma unroll
    for (int o = 32; o; o >>= 1) m = fmaxf(m, __shfl_xor(m, o));
    if (lane == 0) wmax[wid] = m;
    __syncthreads();
    if (threadIdx.x == 0) {
        float bm = wmax[0];
        for (int i = 1; i < nw; ++i) bm = fmaxf(bm, wmax[i]);
        atomicMax(slot, __float_as_uint(bm));
    }
}

// ---------- absmax over f32 tensor (n divisible by 4) ----------
__global__ __launch_bounds__(256) void absmax_kernel(const float* __restrict__ x,
                                                     size_t n4, unsigned* slot) {
    size_t i = (size_t)blockIdx.x * blockDim.x + threadIdx.x;
    size_t stride = (size_t)gridDim.x * blockDim.x;
    const float4* x4 = (const float4*)x;
    float m = 0.0f;
    for (; i < n4; i += stride) {
        float4 v = x4[i];
        m = fmaxf(m, fmaxf(fmaxf(fabsf(v.x), fabsf(v.y)), fmaxf(fabsf(v.z), fabsf(v.w))));
    }
    block_amax_atomic(m, slot);
}

// ---------- quantize f32 -> bf16-int (same layout) ----------
__global__ __launch_bounds__(256) void quant_kernel(const float* __restrict__ x,
                                                    size_t n4, const unsigned* slot,
                                                    u16* __restrict__ out) {
    float s = slot_scale(slot);
    size_t i = (size_t)blockIdx.x * blockDim.x + threadIdx.x;
    size_t stride = (size_t)gridDim.x * blockDim.x;
    const float4* x4 = (const float4*)x;
    ushort4* o4 = (ushort4*)out;
    for (; i < n4; i += stride) {
        float4 v = x4[i];
        ushort4 o;
        o.x = qbits(v.x, s); o.y = qbits(v.y, s);
        o.z = qbits(v.z, s); o.w = qbits(v.w, s);
        o4[i] = o;
    }
}

// ---------- GEMM: C[M,N] = (A_int @ B_int^T) * sA*sB ; A:(M,K) B:(N,K) bf16-ints ----------
__global__ __launch_bounds__(256) void gemm_bt_kernel(const u16* __restrict__ A,
                                                      const u16* __restrict__ B,
                                                      float* __restrict__ C,
                                                      int M, int N, int K,
                                                      const unsigned* __restrict__ sA_slot,
                                                      const unsigned* __restrict__ sB_slot,
                                                      unsigned* out_amax) {
    __shared__ __align__(16) u16 Asm[128 * 64];
    __shared__ __align__(16) u16 Bsm[128 * 64];
    const int tid  = threadIdx.x;
    const int lane = tid & 63;
    const int wave = tid >> 6;
    const int m0 = blockIdx.x * 128;
    const int n0 = blockIdx.y * 128;
    const int wr = (wave >> 1) * 64;
    const int wc = (wave & 1) * 64;
    const int l15 = lane & 15;
    const int l4  = lane >> 4;

    f32x4 zero4 = {0.f, 0.f, 0.f, 0.f};
    f32x4 acc[4][4];
    #pragma unroll
    for (int i = 0; i < 4; ++i)
        #pragma unroll
        for (int j = 0; j < 4; ++j) acc[i][j] = zero4;

    for (int k0 = 0; k0 < K; k0 += 64) {
        __syncthreads();
        #pragma unroll
        for (int c = 0; c < 4; ++c) {
            int cid = c * 256 + tid;          // 1024 chunks of 8 elements
            int row = cid >> 3;
            int col = (cid & 7) << 3;
            *(bf16x8*)&Asm[row * 64 + col] =
                *(const bf16x8*)&A[(size_t)(m0 + row) * K + k0 + col];
            *(bf16x8*)&Bsm[row * 64 + col] =
                *(const bf16x8*)&B[(size_t)(n0 + row) * K + k0 + col];
        }
        __syncthreads();
        #pragma unroll
        for (int kk = 0; kk < 2; ++kk) {
            bf16x8 af[4], bfr[4];
            #pragma unroll
            for (int i = 0; i < 4; ++i)
                af[i] = *(const bf16x8*)&Asm[(wr + i * 16 + l15) * 64 + kk * 32 + l4 * 8];
            #pragma unroll
            for (int j = 0; j < 4; ++j)
                bfr[j] = *(const bf16x8*)&Bsm[(wc + j * 16 + l15) * 64 + kk * 32 + l4 * 8];
            #pragma unroll
            for (int i = 0; i < 4; ++i)
                #pragma unroll
                for (int j = 0; j < 4; ++j)
                    acc[i][j] = __builtin_amdgcn_mfma_f32_16x16x32_bf16(af[i], bfr[j], acc[i][j], 0, 0, 0);
        }
    }

    float scale = slot_scale(sA_slot) * slot_scale(sB_slot);
    float lm = 0.0f;
    #pragma unroll
    for (int i = 0; i < 4; ++i)
        #pragma unroll
        for (int j = 0; j < 4; ++j)
            #pragma unroll
            for (int r = 0; r < 4; ++r) {
                int row = m0 + wr + i * 16 + l4 * 4 + r;
                int col = n0 + wc + j * 16 + l15;
                float v = acc[i][j][r] * scale;
                C[(size_t)row * N + col] = v;
                lm = fmaxf(lm, fabsf(v));
            }
    if (out_amax) block_amax_atomic(lm, out_amax);
}

// ---------- RMSNorm + RoPE in-place on (nrows, 128) f32, + absmax ----------
// grid-stride over rows; one wave per row per iteration.
__global__ __launch_bounds__(256) void rmsrope_kernel(float* __restrict__ x,
                                                      const float* __restrict__ cosb,
                                                      const float* __restrict__ sinb,
                                                      const float* __restrict__ w,
                                                      int s_shift, int nrows,
                                                      unsigned* amax_slot) {
    const int lane = threadIdx.x & 63;
    const int wid  = threadIdx.x >> 6;
    const float wa = w[lane];
    const float wb = w[lane + 64];
    float lm = 0.0f;
    for (int row = blockIdx.x * 4 + wid; row < nrows; row += gridDim.x * 4) {
        int s = row >> s_shift;
        float* xr = x + (size_t)row * 128;
        float a = xr[lane], b = xr[lane + 64];
        float ss = a * a + b * b;
        #pragma unroll
        for (int o = 32; o; o >>= 1) ss += __shfl_xor(ss, o);
        float inv = 1.0f / sqrtf(ss * (1.0f / 128.0f) + 1e-5f);
        float ya = (a * inv) * wa;
        float yb = (b * inv) * wb;
        const float* cr = cosb + (size_t)s * 128;
        const float* sr = sinb + (size_t)s * 128;
        float o0 = ya * cr[lane]      - yb * sr[lane];        // rotate_half: -x[d+64]
        float o1 = yb * cr[lane + 64] + ya * sr[lane + 64];   //              +x[d-64]
        xr[lane] = o0;
        xr[lane + 64] = o1;
        lm = fmaxf(lm, fmaxf(fabsf(o0), fabsf(o1)));
    }
    block_amax_atomic(lm, amax_slot);
}

// ---------- quantize + reorder (S, nh, D) -> (nh, S, D) bf16-ints ----------
__global__ __launch_bounds__(256) void quant_qk_kernel(const float* __restrict__ x,
                                                       int nh, const unsigned* slot,
                                                       u16* __restrict__ out) {
    int tid = blockIdx.x * blockDim.x + threadIdx.x;
    float s = slot_scale(slot);
    int d  = tid & 127;
    int h  = (tid >> 7) % nh;
    int sp = tid / (128 * nh);
    out[((size_t)h * S_LEN + sp) * 128 + d] = qbits(x[tid], s);
}

// ---------- quantize + transpose V: (S, KV, D) -> (KV, D, S) bf16-ints ----------
__global__ __launch_bounds__(256) void quant_v_kernel(const float* __restrict__ x,
                                                      const unsigned* slot,
                                                      u16* __restrict__ out) {
    int tid = blockIdx.x * blockDim.x + threadIdx.x;
    float s = slot_scale(slot);
    int d  = tid & 127;
    int kv = (tid >> 7) & 7;
    int sp = tid >> 10;
    out[((size_t)kv * 128 + d) * S_LEN + sp] = qbits(x[tid], s);
}

// ---------- attention: two-pass flash with quantized P ----------
// Qq:(NH,S,D) Kq:(NKV,S,D) Vt:(NKV,D,S) all bf16-ints. O:(S,NH*D) f32.
__global__ __launch_bounds__(256) void attn_kernel(const u16* __restrict__ Qq,
                                                   const u16* __restrict__ Kq,
                                                   const u16* __restrict__ Vt,
                                                   const unsigned* sq_slot,
                                                   const unsigned* sk_slot,
                                                   const unsigned* sv_slot,
                                                   float* __restrict__ O,
                                                   unsigned* amax_slot) {
    __shared__ __align__(16) u16 Klds[32 * 128];
    __shared__ __align__(16) u16 Vlds[128 * 32];
    __shared__ __align__(16) u16 plds[4][16 * 32];

    const int tid  = threadIdx.x;
    const int lane = tid & 63;
    const int wave = tid >> 6;
    const int qb = blockIdx.x;
    const int h  = blockIdx.y;
    const int kv = h >> 2;                  // n_rep = 4
    const int qr0 = qb * 64 + wave * 16;
    const int l15 = lane & 15;
    const int l4  = lane >> 4;

    const float sq = slot_scale(sq_slot);
    const float sk = slot_scale(sk_slot);
    const float sv = slot_scale(sv_slot);
    const float qk_scale = sq * sk * 0.08838834764831845f;  // D^-0.5
    const float SP = 1.0f / 127.0f;                          // max(p) == 1.0 exactly

    // Q fragments (held in regs for both passes)
    bf16x8 qf[4];
    {
        const u16* qp = Qq + ((size_t)h * S_LEN + qr0 + l15) * 128 + l4 * 8;
        #pragma unroll
        for (int ks = 0; ks < 4; ++ks) qf[ks] = *(const bf16x8*)(qp + ks * 32);
    }

    const int kb_last = qb * 4 + wave;         // last (diagonal) 16-block for this wave
    const int kc_max  = (qb * 4 + 3) >> 1;     // uniform 32-chunk bound for whole block

    float mrow[4], lrow[4];
    #pragma unroll
    for (int r = 0; r < 4; ++r) { mrow[r] = -__builtin_inff(); lrow[r] = 0.0f; }

    // ---- pass 1: row max m and row sum l ----
    for (int kc = 0; kc <= kc_max; ++kc) {
        __syncthreads();
        #pragma unroll
        for (int i = 0; i < 2; ++i) {   // stage K tile 32x128
            int idx = i * 256 + tid;
            int row = idx >> 4, col = (idx & 15) << 3;
            *(bf16x8*)&Klds[row * 128 + col] =
                *(const bf16x8*)&Kq[((size_t)kv * S_LEN + kc * 32 + row) * 128 + col];
        }
        __syncthreads();
        #pragma unroll
        for (int half = 0; half < 2; ++half) {
            int kb = kc * 2 + half;
            if (kb > kb_last) continue;
            f32x4 sacc = {0.f, 0.f, 0.f, 0.f};
            #pragma unroll
            for (int ks = 0; ks < 4; ++ks) {
                bf16x8 kf = *(const bf16x8*)&Klds[(half * 16 + l15) * 128 + ks * 32 + l4 * 8];
                sacc = __builtin_amdgcn_mfma_f32_16x16x32_bf16(qf[ks], kf, sacc, 0, 0, 0);
            }
            bool diag = (kb == kb_last);
            int kpos = kb * 16 + l15;
            #pragma unroll
            for (int r = 0; r < 4; ++r) {
                float sc = sacc[r] * qk_scale;
                int qrow = qr0 + l4 * 4 + r;
                if (diag && kpos > qrow) sc = -__builtin_inff();
                float tm = sc;
                tm = fmaxf(tm, __shfl_xor(tm, 1));
                tm = fmaxf(tm, __shfl_xor(tm, 2));
                tm = fmaxf(tm, __shfl_xor(tm, 4));
                tm = fmaxf(tm, __shfl_xor(tm, 8));
                float mn = fmaxf(mrow[r], tm);
                float p = expf(sc - mn);       // masked: expf(-inf)=0
                float ts = p;
                ts += __shfl_xor(ts, 1);
                ts += __shfl_xor(ts, 2);
                ts += __shfl_xor(ts, 4);
                ts += __shfl_xor(ts, 8);
                lrow[r] = lrow[r] * expf(mrow[r] - mn) + ts;
                mrow[r] = mn;
            }
        }
    }

    // ---- pass 2: quantized P @ V ----
    f32x4 oacc[8];
    {
        f32x4 zero4 = {0.f, 0.f, 0.f, 0.f};
        #pragma unroll
        for (int dt = 0; dt < 8; ++dt) oacc[dt] = zero4;
    }
    for (int kc = 0; kc <= kc_max; ++kc) {
        __syncthreads();
        #pragma unroll
        for (int i = 0; i < 2; ++i) {   // stage K (32x128) and V^T (128x32) tiles
            int idx = i * 256 + tid;
            int krow = idx >> 4, kcol = (idx & 15) << 3;
            *(bf16x8*)&Klds[krow * 128 + kcol] =
                *(const bf16x8*)&Kq[((size_t)kv * S_LEN + kc * 32 + krow) * 128 + kcol];
            int vrow = idx >> 2, vcol = (idx & 3) << 3;
            *(bf16x8*)&Vlds[vrow * 32 + vcol] =
                *(const bf16x8*)&Vt[((size_t)kv * 128 + vrow) * S_LEN + kc * 32 + vcol];
        }
        __syncthreads();
        #pragma unroll
        for (int half = 0; half < 2; ++half) {
            int kb = kc * 2 + half;
            u16 pz[4];
            if (kb <= kb_last) {
                f32x4 sacc = {0.f, 0.f, 0.f, 0.f};
                #pragma unroll
                for (int ks = 0; ks < 4; ++ks) {
                    bf16x8 kf = *(const bf16x8*)&Klds[(half * 16 + l15) * 128 + ks * 32 + l4 * 8];
                    sacc = __builtin_amdgcn_mfma_f32_16x16x32_bf16(qf[ks], kf, sacc, 0, 0, 0);
                }
                bool diag = (kb == kb_last);
                int kpos = kb * 16 + l15;
                #pragma unroll
                for (int r = 0; r < 4; ++r) {
                    float sc = sacc[r] * qk_scale;
                    int qrow = qr0 + l4 * 4 + r;
                    if (diag && kpos > qrow) sc = -__builtin_inff();
                    float p = expf(sc - mrow[r]) / lrow[r];
                    float q = rintf(p / SP);   // p<=1 -> no clip needed
                    pz[r] = (u16)(__float_as_uint(q) >> 16);
                }
            } else {
                #pragma unroll
                for (int r = 0; r < 4; ++r) pz[r] = 0;
            }
            #pragma unroll
            for (int r = 0; r < 4; ++r)
                plds[wave][(l4 * 4 + r) * 32 + half * 16 + l15] = pz[r];
        }
        __syncthreads();   // order plds writes (cross-lane) before fragment reads
        bf16x8 pf = *(const bf16x8*)&plds[wave][l15 * 32 + l4 * 8];
        #pragma unroll
        for (int dt = 0; dt < 8; ++dt) {
            bf16x8 vf = *(const bf16x8*)&Vlds[(dt * 16 + l15) * 32 + l4 * 8];
            oacc[dt] = __builtin_amdgcn_mfma_f32_16x16x32_bf16(pf, vf, oacc[dt], 0, 0, 0);
        }
    }

    // epilogue: dequant (s_p * s_v), write O, absmax
    float osc = SP * sv;
    float lm = 0.0f;
    #pragma unroll
    for (int dt = 0; dt < 8; ++dt)
        #pragma unroll
        for (int r = 0; r < 4; ++r) {
            int qrow = qr0 + l4 * 4 + r;
            int col = h * 128 + dt * 16 + l15;
            float v = oacc[dt][r] * osc;
            O[(size_t)qrow * (NH * 128) + col] = v;
            lm = fmaxf(lm, fabsf(v));
        }
    block_amax_atomic(lm, amax_slot);
}

// ---------- host ----------
extern "C" void kernel_launch(void* const* d_in, const int* in_sizes, int n_in,
                              void* d_out, int out_size, void* d_ws, size_t ws_size,
                              hipStream_t stream) {
    const float* hs   = (const float*)d_in[0];
    const float* cosb = (const float*)d_in[1];
    const float* sinb = (const float*)d_in[2];
    // d_in[3] attention_mask: causal, implemented analytically
    const float* Wq   = (const float*)d_in[4];
    const float* Wk   = (const float*)d_in[5];
    const float* Wv   = (const float*)d_in[6];
    const float* Wo   = (const float*)d_in[7];
    const float* qnw  = (const float*)d_in[8];
    const float* knw  = (const float*)d_in[9];
    float* out = (float*)d_out;

    char* ws = (char*)d_ws;
    unsigned* slots = (unsigned*)ws;
    // slots: 0 hs, 1 Wq, 2 Wk, 3 Wv, 4 Wo, 5 q, 6 k, 7 v, 8 attn
    size_t off = 256;
    auto take = [&](size_t bytes) { size_t o = off; off += (bytes + 255) & ~(size_t)255; return o; };
    u16*   hsq  = (u16*)(ws + take((size_t)S_LEN * HIDD * 2));       // 16 MB
    u16*   Wqq  = (u16*)(ws + take((size_t)NH * HD * HIDD * 2));     // 32 MB
    u16*   Wkq  = (u16*)(ws + take((size_t)NKV * HD * HIDD * 2));    //  8 MB
    u16*   Wvq  = (u16*)(ws + take((size_t)NKV * HD * HIDD * 2));    //  8 MB
    u16*   Woq  = (u16*)(ws + take((size_t)HIDD * NH * HD * 2));     // 32 MB
    float* qf   = (float*)(ws + take((size_t)S_LEN * NH * HD * 4));  // 32 MB (reused as attn out)
    float* kf   = (float*)(ws + take((size_t)S_LEN * NKV * HD * 4)); //  8 MB
    float* vf   = (float*)(ws + take((size_t)S_LEN * NKV * HD * 4)); //  8 MB
    u16*   qq   = (u16*)(ws + take((size_t)NH * S_LEN * HD * 2));    // 16 MB
    u16*   kq   = (u16*)(ws + take((size_t)NKV * S_LEN * HD * 2));   //  4 MB
    u16*   vtq  = (u16*)(ws + take((size_t)NKV * HD * S_LEN * 2));   //  4 MB
    float* attnf = qf;     // q f32 dead after quant_qk
    u16*   attnq = hsq;    // hs_q dead after the three projections

    hipMemsetAsync(ws, 0, 64, stream);

    const size_t n_hs = (size_t)S_LEN * HIDD;
    const size_t n_wq = (size_t)NH * HD * HIDD;
    const size_t n_wk = (size_t)NKV * HD * HIDD;

    absmax_kernel<<<1024, 256, 0, stream>>>(hs, n_hs / 4, slots + 0);
    absmax_kernel<<<1024, 256, 0, stream>>>(Wq, n_wq / 4, slots + 1);
    absmax_kernel<<<512,  256, 0, stream>>>(Wk, n_wk / 4, slots + 2);
    absmax_kernel<<<512,  256, 0, stream>>>(Wv, n_wk / 4, slots + 3);
    absmax_kernel<<<1024, 256, 0, stream>>>(Wo, n_wq / 4, slots + 4);

    quant_kernel<<<2048, 256, 0, stream>>>(hs, n_hs / 4, slots + 0, hsq);
    quant_kernel<<<2048, 256, 0, stream>>>(Wq, n_wq / 4, slots + 1, Wqq);
    quant_kernel<<<1024, 256, 0, stream>>>(Wk, n_wk / 4, slots + 2, Wkq);
    quant_kernel<<<1024, 256, 0, stream>>>(Wv, n_wk / 4, slots + 3, Wvq);
    quant_kernel<<<2048, 256, 0, stream>>>(Wo, n_wq / 4, slots + 4, Woq);

    dim3 gq(S_LEN / 128, (NH * HD) / 128);    // (16, 32)
    dim3 gk(S_LEN / 128, (NKV * HD) / 128);   // (16, 8)
    gemm_bt_kernel<<<gq, 256, 0, stream>>>(hsq, Wqq, qf, S_LEN, NH * HD, HIDD,
                                           slots + 0, slots + 1, nullptr);
    gemm_bt_kernel<<<gk, 256, 0, stream>>>(hsq, Wkq, kf, S_LEN, NKV * HD, HIDD,
                                           slots + 0, slots + 2, nullptr);
    gemm_bt_kernel<<<gk, 256, 0, stream>>>(hsq, Wvq, vf, S_LEN, NKV * HD, HIDD,
                                           slots + 0, slots + 3, slots + 7);

    rmsrope_kernel<<<1024, 256, 0, stream>>>(qf, cosb, sinb, qnw, 5, S_LEN * NH, slots + 5);
    rmsrope_kernel<<<512,  256, 0, stream>>>(kf, cosb, sinb, knw, 3, S_LEN * NKV, slots + 6);

    quant_qk_kernel<<<(int)((size_t)S_LEN * NH * HD / 256), 256, 0, stream>>>(qf, NH, slots + 5, qq);
    quant_qk_kernel<<<(int)((size_t)S_LEN * NKV * HD / 256), 256, 0, stream>>>(kf, NKV, slots + 6, kq);
    quant_v_kernel<<<(int)((size_t)S_LEN * NKV * HD / 256), 256, 0, stream>>>(vf, slots + 7, vtq);

    attn_kernel<<<dim3(S_LEN / 64, NH), 256, 0, stream>>>(qq, kq, vtq,
                                                          slots + 5, slots + 6, slots + 7,
                                                          attnf, slots + 8);

    quant_kernel<<<2048, 256, 0, stream>>>(attnf, n_hs / 4, slots + 8, attnq);
    gemm_bt_kernel<<<gq, 256, 0, stream>>>(attnq, Woq, out, S_LEN, NH * HD, HIDD,
                                           slots + 8, slots + 4, nullptr);
    (void)in_sizes; (void)n_in; (void)out_size; (void)ws_size;
}

// Round 3
// 752.749 us; speedup vs baseline: 3.0286x; 1.6354x over previous
//
#include <hip/hip_runtime.h>
#include <hip/hip_bf16.h>
#include <math.h>
#include <stdint.h>

// Problem constants
#define S_LEN 2048
#define NH    32
#define NKV   8
#define HD    128
#define HIDD  4096

typedef unsigned short u16;
typedef __attribute__((ext_vector_type(8))) short bf16x8;
typedef __attribute__((ext_vector_type(4))) float f32x4;

// async global->LDS, 16B per lane. LDS dest is wave-uniform base + lane*16.
#define GLD16(g, l) __builtin_amdgcn_global_load_lds( \
    (const __attribute__((address_space(1))) void*)(g), \
    (__attribute__((address_space(3))) void*)(l), 16, 0, 0)

// ---------- helpers ----------

// scale = max(absmax, 1e-5) / 127  (exact f32 division, matches jnp)
__device__ __forceinline__ float slot_scale(const unsigned* slot) {
    return fmaxf(__uint_as_float(*slot), 1e-5f) / 127.0f;
}

// quantized integer (as float) -> bf16 bits. Values are integers in [-128,127],
// whose f32 representation has zero low 16 bits -> truncation is exact.
__device__ __forceinline__ u16 qbits(float x, float s) {
    float q = rintf(x / s);
    q = fminf(fmaxf(q, -128.0f), 127.0f);
    return (u16)(__float_as_uint(q) >> 16);
}

// block-level absmax -> ONE atomic per block
__device__ __forceinline__ void block_amax_atomic(float m, unsigned* slot) {
    __shared__ float wmax[8];
    const int lane = threadIdx.x & 63;
    const int wid  = threadIdx.x >> 6;
    const int nw   = blockDim.x >> 6;
    #pragma unroll
    for (int o = 32; o; o >>= 1) m = fmaxf(m, __shfl_xor(m, o));
    if (lane == 0) wmax[wid] = m;
    __syncthreads();
    if (threadIdx.x == 0) {
        float bm = wmax[0];
        for (int i = 1; i < nw; ++i) bm = fmaxf(bm, wmax[i]);
        atomicMax(slot, __float_as_uint(bm));
    }
}

// ---------- absmax over f32 tensor (n divisible by 4) ----------
__global__ __launch_bounds__(256) void absmax_kernel(const float* __restrict__ x,
                                                     size_t n4, unsigned* slot) {
    size_t i = (size_t)blockIdx.x * blockDim.x + threadIdx.x;
    size_t stride = (size_t)gridDim.x * blockDim.x;
    const float4* x4 = (const float4*)x;
    float m = 0.0f;
    for (; i < n4; i += stride) {
        float4 v = x4[i];
        m = fmaxf(m, fmaxf(fmaxf(fabsf(v.x), fabsf(v.y)), fmaxf(fabsf(v.z), fabsf(v.w))));
    }
    block_amax_atomic(m, slot);
}

// ---------- quantize f32 -> bf16-int (same layout) ----------
__global__ __launch_bounds__(256) void quant_kernel(const float* __restrict__ x,
                                                    size_t n4, const unsigned* slot,
                                                    u16* __restrict__ out) {
    float s = slot_scale(slot);
    size_t i = (size_t)blockIdx.x * blockDim.x + threadIdx.x;
    size_t stride = (size_t)gridDim.x * blockDim.x;
    const float4* x4 = (const float4*)x;
    ushort4* o4 = (ushort4*)out;
    for (; i < n4; i += stride) {
        float4 v = x4[i];
        ushort4 o;
        o.x = qbits(v.x, s); o.y = qbits(v.y, s);
        o.z = qbits(v.z, s); o.w = qbits(v.w, s);
        o4[i] = o;
    }
}

// ---------- GEMM body (m97 recipe): 128x128 tile, BK=64, global_load_lds x16 ----------
__device__ __forceinline__ void gemm_body(const u16* __restrict__ A,
                                          const u16* __restrict__ B,
                                          float* __restrict__ C,
                                          int m0, int n0, int N, int K,
                                          float scale, unsigned* out_amax,
                                          u16* Asm, u16* Bsm) {
    const int tid  = threadIdx.x;
    const int lane = tid & 63;
    const int wave = tid >> 6;
    const int wr = (wave >> 1) * 64;
    const int wc = (wave & 1) * 64;
    const int l15 = lane & 15;
    const int l4  = lane >> 4;
    const int srow = lane >> 3;        // staging row within 8-row segment
    const int scol = (lane & 7) * 8;   // staging col (u16)

    f32x4 acc[4][4];
    #pragma unroll
    for (int i = 0; i < 4; ++i)
        #pragma unroll
        for (int j = 0; j < 4; ++j) acc[i][j] = (f32x4){0.f, 0.f, 0.f, 0.f};

    for (int k0 = 0; k0 < K; k0 += 64) {
        __syncthreads();
        #pragma unroll
        for (int c = 0; c < 4; ++c) {
            int seg = wave * 4 + c;            // 16 segments of 8 rows x 64 cols
            int gr  = seg * 8 + srow;
            GLD16(&A[(size_t)(m0 + gr) * K + k0 + scol], &Asm[seg * 512]);
            GLD16(&B[(size_t)(n0 + gr) * K + k0 + scol], &Bsm[seg * 512]);
        }
        __syncthreads();   // compiler drains vmcnt(0) before s_barrier
        #pragma unroll
        for (int kk = 0; kk < 2; ++kk) {
            bf16x8 af[4], bfr[4];
            #pragma unroll
            for (int i = 0; i < 4; ++i)
                af[i] = *(const bf16x8*)&Asm[(wr + i * 16 + l15) * 64 + kk * 32 + l4 * 8];
            #pragma unroll
            for (int j = 0; j < 4; ++j)
                bfr[j] = *(const bf16x8*)&Bsm[(wc + j * 16 + l15) * 64 + kk * 32 + l4 * 8];
            #pragma unroll
            for (int i = 0; i < 4; ++i)
                #pragma unroll
                for (int j = 0; j < 4; ++j)
                    acc[i][j] = __builtin_amdgcn_mfma_f32_16x16x32_bf16(af[i], bfr[j], acc[i][j], 0, 0, 0);
        }
    }

    float lm = 0.0f;
    #pragma unroll
    for (int i = 0; i < 4; ++i)
        #pragma unroll
        for (int j = 0; j < 4; ++j)
            #pragma unroll
            for (int r = 0; r < 4; ++r) {
                int row = m0 + wr + i * 16 + l4 * 4 + r;
                int col = n0 + wc + j * 16 + l15;
                float v = acc[i][j][r] * scale;
                C[(size_t)row * N + col] = v;
                lm = fmaxf(lm, fabsf(v));
            }
    if (out_amax) block_amax_atomic(lm, out_amax);
}

__global__ __launch_bounds__(256) void gemm_bt_kernel(const u16* __restrict__ A,
                                                      const u16* __restrict__ B,
                                                      float* __restrict__ C,
                                                      int N, int K,
                                                      const unsigned* __restrict__ sA_slot,
                                                      const unsigned* __restrict__ sB_slot,
                                                      unsigned* out_amax) {
    __shared__ __align__(16) u16 Asm[128 * 64];
    __shared__ __align__(16) u16 Bsm[128 * 64];
    float scale = slot_scale(sA_slot) * slot_scale(sB_slot);
    gemm_body(A, B, C, blockIdx.x * 128, blockIdx.y * 128, N, K, scale, out_amax, Asm, Bsm);
}

// K and V projections fused into one dispatch (256 blocks -> full CU coverage)
__global__ __launch_bounds__(256) void gemm_kv_kernel(const u16* __restrict__ A,
                                                      const u16* __restrict__ Bk,
                                                      const u16* __restrict__ Bv,
                                                      float* __restrict__ Ck,
                                                      float* __restrict__ Cv,
                                                      int K,
                                                      const unsigned* __restrict__ sA_slot,
                                                      const unsigned* __restrict__ sK_slot,
                                                      const unsigned* __restrict__ sV_slot,
                                                      unsigned* v_amax) {
    __shared__ __align__(16) u16 Asm[128 * 64];
    __shared__ __align__(16) u16 Bsm[128 * 64];
    const bool isv = blockIdx.y >= 8;
    const u16* B = isv ? Bv : Bk;
    float*     C = isv ? Cv : Ck;
    float scale = slot_scale(sA_slot) * slot_scale(isv ? sV_slot : sK_slot);
    gemm_body(A, B, C, blockIdx.x * 128, (blockIdx.y & 7) * 128, NKV * HD, K, scale,
              isv ? v_amax : nullptr, Asm, Bsm);
}

// ---------- RMSNorm + RoPE in-place on (nrows, 128) f32, + absmax ----------
__global__ __launch_bounds__(256) void rmsrope_kernel(float* __restrict__ x,
                                                      const float* __restrict__ cosb,
                                                      const float* __restrict__ sinb,
                                                      const float* __restrict__ w,
                                                      int s_shift, int nrows,
                                                      unsigned* amax_slot) {
    const int lane = threadIdx.x & 63;
    const int wid  = threadIdx.x >> 6;
    const float wa = w[lane];
    const float wb = w[lane + 64];
    float lm = 0.0f;
    for (int row = blockIdx.x * 4 + wid; row < nrows; row += gridDim.x * 4) {
        int s = row >> s_shift;
        float* xr = x + (size_t)row * 128;
        float a = xr[lane], b = xr[lane + 64];
        float ss = a * a + b * b;
        #pragma unroll
        for (int o = 32; o; o >>= 1) ss += __shfl_xor(ss, o);
        float inv = 1.0f / sqrtf(ss * (1.0f / 128.0f) + 1e-5f);
        float ya = (a * inv) * wa;
        float yb = (b * inv) * wb;
        const float* cr = cosb + (size_t)s * 128;
        const float* sr = sinb + (size_t)s * 128;
        float o0 = ya * cr[lane]      - yb * sr[lane];
        float o1 = yb * cr[lane + 64] + ya * sr[lane + 64];
        xr[lane] = o0;
        xr[lane + 64] = o1;
        lm = fmaxf(lm, fmaxf(fabsf(o0), fabsf(o1)));
    }
    block_amax_atomic(lm, amax_slot);
}

// ---------- quantize + reorder (S, nh, D) -> (nh, S, D) bf16-ints ----------
__global__ __launch_bounds__(256) void quant_qk_kernel(const float* __restrict__ x,
                                                       int nh, const unsigned* slot,
                                                       u16* __restrict__ out) {
    int tid = blockIdx.x * blockDim.x + threadIdx.x;
    float s = slot_scale(slot);
    int d  = tid & 127;
    int h  = (tid >> 7) % nh;
    int sp = tid / (128 * nh);
    out[((size_t)h * S_LEN + sp) * 128 + d] = qbits(x[tid], s);
}

// ---------- quantize + transpose V: (S, KV, D) -> (KV, D, S) via LDS tile ----------
__global__ __launch_bounds__(256) void quant_v_kernel(const float* __restrict__ x,
                                                      const unsigned* slot,
                                                      u16* __restrict__ out) {
    __shared__ u16 t16[64][34];   // pad -> conflict-light column reads
    const float s = slot_scale(slot);
    const int t   = threadIdx.x;
    const int sp0 = blockIdx.x * 64;
    const int d0  = blockIdx.y * 32;
    const int kvh = blockIdx.z;
    const int dl = t & 31;
    const int sb = t >> 5;            // 0..7
    #pragma unroll
    for (int j = 0; j < 8; ++j) {
        int spl = sb + j * 8;
        float v = x[((size_t)(sp0 + spl) * NKV + kvh) * 128 + d0 + dl];
        t16[spl][dl] = qbits(v, s);
    }
    __syncthreads();
    const int dd = t >> 3;            // 0..31
    const int ch = t & 7;             // 0..7
    bf16x8 o;
    #pragma unroll
    for (int j = 0; j < 8; ++j) o[j] = (short)t16[ch * 8 + j][dd];
    *(bf16x8*)&out[((size_t)kvh * 128 + d0 + dd) * S_LEN + sp0 + ch * 8] = o;
}

// ---------- attention: two-pass flash with quantized P ----------
// Qq:(NH,S,D) Kq:(NKV,S,D) Vt:(NKV,D,S) all bf16-ints. O:(S,NH*D) f32.
// Padded LDS strides kill the 16-way bank conflicts of D=128 row-major tiles.
// Each block processes q-tile pair (x, 31-x) -> uniform causal work.
__global__ __launch_bounds__(256) void attn_kernel(const u16* __restrict__ Qq,
                                                   const u16* __restrict__ Kq,
                                                   const u16* __restrict__ Vt,
                                                   const unsigned* sq_slot,
                                                   const unsigned* sk_slot,
                                                   const unsigned* sv_slot,
                                                   float* __restrict__ O,
                                                   unsigned* amax_slot) {
    __shared__ __align__(16) u16 Klds[32 * 136];     // row stride 136 u16 = 272B
    __shared__ __align__(16) u16 Vlds[128 * 40];     // row stride 40 u16 = 80B
    __shared__ __align__(16) u16 plds[4][16 * 40];   // per-wave P tile

    const int tid  = threadIdx.x;
    const int lane = tid & 63;
    const int wave = tid >> 6;
    const int h  = blockIdx.y;
    const int kv = h >> 2;                  // n_rep = 4
    const int l15 = lane & 15;
    const int l4  = lane >> 4;

    const float sq = slot_scale(sq_slot);
    const float sk = slot_scale(sk_slot);
    const float sv = slot_scale(sv_slot);
    const float qk_scale = sq * sk * 0.08838834764831845f;  // D^-0.5
    const float osc = (1.0f / 127.0f) * sv;   // s_p exactly 1/127 (row 0 p=1.0)

    float lm = 0.0f;

    #pragma unroll 1
    for (int tpass = 0; tpass < 2; ++tpass) {
        const int qt  = tpass ? (31 - (int)blockIdx.x) : (int)blockIdx.x;
        const int qr0 = qt * 64 + wave * 16;
        const int kb_last = qt * 4 + wave;
        const int kc_max  = qt * 2 + 1;

        bf16x8 qf[4];
        {
            const u16* qp = Qq + ((size_t)h * S_LEN + qr0 + l15) * 128 + l4 * 8;
            #pragma unroll
            for (int ks = 0; ks < 4; ++ks) qf[ks] = *(const bf16x8*)(qp + ks * 32);
        }

        float mrow[4], lrow[4];
        #pragma unroll
        for (int r = 0; r < 4; ++r) { mrow[r] = -__builtin_inff(); lrow[r] = 0.0f; }

        // ---- pass 1: row max m and row sum l ----
        for (int kc = 0; kc <= kc_max; ++kc) {
            __syncthreads();
            #pragma unroll
            for (int i = 0; i < 2; ++i) {
                int idx = i * 256 + tid;
                int row = idx >> 4, col = (idx & 15) << 3;
                *(bf16x8*)&Klds[row * 136 + col] =
                    *(const bf16x8*)&Kq[((size_t)kv * S_LEN + kc * 32 + row) * 128 + col];
            }
            __syncthreads();
            #pragma unroll
            for (int half = 0; half < 2; ++half) {
                int kb = kc * 2 + half;
                if (kb > kb_last) continue;
                f32x4 sacc = {0.f, 0.f, 0.f, 0.f};
                #pragma unroll
                for (int ks = 0; ks < 4; ++ks) {
                    bf16x8 kf = *(const bf16x8*)&Klds[(half * 16 + l15) * 136 + ks * 32 + l4 * 8];
                    sacc = __builtin_amdgcn_mfma_f32_16x16x32_bf16(qf[ks], kf, sacc, 0, 0, 0);
                }
                bool diag = (kb == kb_last);
                int kpos = kb * 16 + l15;
                #pragma unroll
                for (int r = 0; r < 4; ++r) {
                    float sc = sacc[r] * qk_scale;
                    int qrow = qr0 + l4 * 4 + r;
                    if (diag && kpos > qrow) sc = -__builtin_inff();
                    float tm = sc;
                    tm = fmaxf(tm, __shfl_xor(tm, 1));
                    tm = fmaxf(tm, __shfl_xor(tm, 2));
                    tm = fmaxf(tm, __shfl_xor(tm, 4));
                    tm = fmaxf(tm, __shfl_xor(tm, 8));
                    float mn = fmaxf(mrow[r], tm);
                    float p = __expf(sc - mn);
                    float ts = p;
                    ts += __shfl_xor(ts, 1);
                    ts += __shfl_xor(ts, 2);
                    ts += __shfl_xor(ts, 4);
                    ts += __shfl_xor(ts, 8);
                    lrow[r] = lrow[r] * __expf(mrow[r] - mn) + ts;
                    mrow[r] = mn;
                }
            }
        }

        float rl127[4];
        #pragma unroll
        for (int r = 0; r < 4; ++r) rl127[r] = 127.0f / lrow[r];  // one exact div per row

        // ---- pass 2: quantized P @ V ----
        f32x4 oacc[8];
        #pragma unroll
        for (int dt = 0; dt < 8; ++dt) oacc[dt] = (f32x4){0.f, 0.f, 0.f, 0.f};

        for (int kc = 0; kc <= kc_max; ++kc) {
            __syncthreads();
            #pragma unroll
            for (int i = 0; i < 2; ++i) {
                int idx = i * 256 + tid;
                int krow = idx >> 4, kcol = (idx & 15) << 3;
                *(bf16x8*)&Klds[krow * 136 + kcol] =
                    *(const bf16x8*)&Kq[((size_t)kv * S_LEN + kc * 32 + krow) * 128 + kcol];
                int vrow = idx >> 2, vcol = (idx & 3) << 3;
                *(bf16x8*)&Vlds[vrow * 40 + vcol] =
                    *(const bf16x8*)&Vt[((size_t)kv * 128 + vrow) * S_LEN + kc * 32 + vcol];
            }
            __syncthreads();
            #pragma unroll
            for (int half = 0; half < 2; ++half) {
                int kb = kc * 2 + half;
                u16 pz[4] = {0, 0, 0, 0};
                if (kb <= kb_last) {
                    f32x4 sacc = {0.f, 0.f, 0.f, 0.f};
                    #pragma unroll
                    for (int ks = 0; ks < 4; ++ks) {
                        bf16x8 kf = *(const bf16x8*)&Klds[(half * 16 + l15) * 136 + ks * 32 + l4 * 8];
                        sacc = __builtin_amdgcn_mfma_f32_16x16x32_bf16(qf[ks], kf, sacc, 0, 0, 0);
                    }
                    bool diag = (kb == kb_last);
                    int kpos = kb * 16 + l15;
                    #pragma unroll
                    for (int r = 0; r < 4; ++r) {
                        float sc = sacc[r] * qk_scale;
                        int qrow = qr0 + l4 * 4 + r;
                        float pq = (diag && kpos > qrow) ? 0.0f
                                 : rintf(__expf(sc - mrow[r]) * rl127[r]);
                        pz[r] = (u16)(__float_as_uint(pq) >> 16);
                    }
                }
                #pragma unroll
                for (int r = 0; r < 4; ++r)
                    plds[wave][(l4 * 4 + r) * 40 + half * 16 + l15] = pz[r];
            }
            // per-wave LDS round trip; compiler orders ds_write->ds_read via lgkmcnt
            bf16x8 pf = *(const bf16x8*)&plds[wave][l15 * 40 + l4 * 8];
            #pragma unroll
            for (int dt = 0; dt < 8; ++dt) {
                bf16x8 vf = *(const bf16x8*)&Vlds[(dt * 16 + l15) * 40 + l4 * 8];
                oacc[dt] = __builtin_amdgcn_mfma_f32_16x16x32_bf16(pf, vf, oacc[dt], 0, 0, 0);
            }
        }

        #pragma unroll
        for (int dt = 0; dt < 8; ++dt)
            #pragma unroll
            for (int r = 0; r < 4; ++r) {
                int qrow = qr0 + l4 * 4 + r;
                float v = oacc[dt][r] * osc;
                O[(size_t)qrow * (NH * 128) + h * 128 + dt * 16 + l15] = v;
                lm = fmaxf(lm, fabsf(v));
            }
    }
    block_amax_atomic(lm, amax_slot);
}

// ---------- host ----------
extern "C" void kernel_launch(void* const* d_in, const int* in_sizes, int n_in,
                              void* d_out, int out_size, void* d_ws, size_t ws_size,
                              hipStream_t stream) {
    const float* hs   = (const float*)d_in[0];
    const float* cosb = (const float*)d_in[1];
    const float* sinb = (const float*)d_in[2];
    // d_in[3] attention_mask: causal, implemented analytically
    const float* Wq   = (const float*)d_in[4];
    const float* Wk   = (const float*)d_in[5];
    const float* Wv   = (const float*)d_in[6];
    const float* Wo   = (const float*)d_in[7];
    const float* qnw  = (const float*)d_in[8];
    const float* knw  = (const float*)d_in[9];
    float* out = (float*)d_out;

    char* ws = (char*)d_ws;
    unsigned* slots = (unsigned*)ws;
    // slots: 0 hs, 1 Wq, 2 Wk, 3 Wv, 4 Wo, 5 q, 6 k, 7 v, 8 attn
    size_t off = 256;
    auto take = [&](size_t bytes) { size_t o = off; off += (bytes + 255) & ~(size_t)255; return o; };
    u16*   hsq  = (u16*)(ws + take((size_t)S_LEN * HIDD * 2));
    u16*   Wqq  = (u16*)(ws + take((size_t)NH * HD * HIDD * 2));
    u16*   Wkq  = (u16*)(ws + take((size_t)NKV * HD * HIDD * 2));
    u16*   Wvq  = (u16*)(ws + take((size_t)NKV * HD * HIDD * 2));
    u16*   Woq  = (u16*)(ws + take((size_t)HIDD * NH * HD * 2));
    float* qf   = (float*)(ws + take((size_t)S_LEN * NH * HD * 4));
    float* kf   = (float*)(ws + take((size_t)S_LEN * NKV * HD * 4));
    float* vf   = (float*)(ws + take((size_t)S_LEN * NKV * HD * 4));
    u16*   qq   = (u16*)(ws + take((size_t)NH * S_LEN * HD * 2));
    u16*   kq   = (u16*)(ws + take((size_t)NKV * S_LEN * HD * 2));
    u16*   vtq  = (u16*)(ws + take((size_t)NKV * HD * S_LEN * 2));
    float* attnf = qf;     // q f32 dead after quant_qk
    u16*   attnq = hsq;    // hs_q dead after the three projections

    hipMemsetAsync(ws, 0, 64, stream);

    const size_t n_hs = (size_t)S_LEN * HIDD;
    const size_t n_wq = (size_t)NH * HD * HIDD;
    const size_t n_wk = (size_t)NKV * HD * HIDD;

    absmax_kernel<<<1024, 256, 0, stream>>>(hs, n_hs / 4, slots + 0);
    absmax_kernel<<<1024, 256, 0, stream>>>(Wq, n_wq / 4, slots + 1);
    absmax_kernel<<<512,  256, 0, stream>>>(Wk, n_wk / 4, slots + 2);
    absmax_kernel<<<512,  256, 0, stream>>>(Wv, n_wk / 4, slots + 3);
    absmax_kernel<<<1024, 256, 0, stream>>>(Wo, n_wq / 4, slots + 4);

    quant_kernel<<<2048, 256, 0, stream>>>(hs, n_hs / 4, slots + 0, hsq);
    quant_kernel<<<2048, 256, 0, stream>>>(Wq, n_wq / 4, slots + 1, Wqq);
    quant_kernel<<<1024, 256, 0, stream>>>(Wk, n_wk / 4, slots + 2, Wkq);
    quant_kernel<<<1024, 256, 0, stream>>>(Wv, n_wk / 4, slots + 3, Wvq);
    quant_kernel<<<2048, 256, 0, stream>>>(Wo, n_wq / 4, slots + 4, Woq);

    gemm_bt_kernel<<<dim3(16, 32), 256, 0, stream>>>(hsq, Wqq, qf, NH * HD, HIDD,
                                                     slots + 0, slots + 1, nullptr);
    gemm_kv_kernel<<<dim3(16, 16), 256, 0, stream>>>(hsq, Wkq, Wvq, kf, vf, HIDD,
                                                     slots + 0, slots + 2, slots + 3, slots + 7);

    rmsrope_kernel<<<1024, 256, 0, stream>>>(qf, cosb, sinb, qnw, 5, S_LEN * NH, slots + 5);
    rmsrope_kernel<<<512,  256, 0, stream>>>(kf, cosb, sinb, knw, 3, S_LEN * NKV, slots + 6);

    quant_qk_kernel<<<(int)((size_t)S_LEN * NH * HD / 256), 256, 0, stream>>>(qf, NH, slots + 5, qq);
    quant_qk_kernel<<<(int)((size_t)S_LEN * NKV * HD / 256), 256, 0, stream>>>(kf, NKV, slots + 6, kq);
    quant_v_kernel<<<dim3(32, 4, 8), 256, 0, stream>>>(vf, slots + 7, vtq);

    attn_kernel<<<dim3(16, NH), 256, 0, stream>>>(qq, kq, vtq,
                                                  slots + 5, slots + 6, slots + 7,
                                                  attnf, slots + 8);

    quant_kernel<<<2048, 256, 0, stream>>>(attnf, n_hs / 4, slots + 8, attnq);
    gemm_bt_kernel<<<dim3(16, 32), 256, 0, stream>>>(attnq, Woq, out, NH * HD, HIDD,
                                                     slots + 8, slots + 4, nullptr);
    (void)in_sizes; (void)n_in; (void)out_size; (void)ws_size;
}

// Round 4
// 599.749 us; speedup vs baseline: 3.8012x; 1.2551x over previous
//
#include <hip/hip_runtime.h>
#include <hip/hip_bf16.h>
#include <math.h>
#include <stdint.h>

// Problem constants
#define S_LEN 2048
#define NH    32
#define NKV   8
#define HD    128
#define HIDD  4096

typedef unsigned short u16;
typedef __attribute__((ext_vector_type(8))) short bf16x8;
typedef __attribute__((ext_vector_type(4))) float f32x4;

// async global->LDS, 16B per lane. LDS dest is wave-uniform base + lane*16.
#define GLD16(g, l) __builtin_amdgcn_global_load_lds( \
    (const __attribute__((address_space(1))) void*)(g), \
    (__attribute__((address_space(3))) void*)(l), 16, 0, 0)

// ---------- helpers ----------

__device__ __forceinline__ float slot_scale(const unsigned* slot) {
    return fmaxf(__uint_as_float(*slot), 1e-5f) / 127.0f;
}

__device__ __forceinline__ u16 qbits(float x, float s) {
    float q = rintf(x / s);
    q = fminf(fmaxf(q, -128.0f), 127.0f);
    return (u16)(__float_as_uint(q) >> 16);
}

__device__ __forceinline__ void block_amax_atomic(float m, unsigned* slot) {
    __shared__ float wmax[8];
    const int lane = threadIdx.x & 63;
    const int wid  = threadIdx.x >> 6;
    const int nw   = blockDim.x >> 6;
    #pragma unroll
    for (int o = 32; o; o >>= 1) m = fmaxf(m, __shfl_xor(m, o));
    if (lane == 0) wmax[wid] = m;
    __syncthreads();
    if (threadIdx.x == 0) {
        float bm = wmax[0];
        for (int i = 1; i < nw; ++i) bm = fmaxf(bm, wmax[i]);
        atomicMax(slot, __float_as_uint(bm));
    }
}

// ---------- batched absmax over 5 f32 tensors ----------
struct Amax5Args { const float* p[5]; size_t n4[5]; };
__global__ __launch_bounds__(256) void absmax5_kernel(Amax5Args a, unsigned* slots) {
    const int t = blockIdx.y;
    const float4* x4 = (const float4*)a.p[t];
    const size_t n4 = a.n4[t];
    size_t i = (size_t)blockIdx.x * blockDim.x + threadIdx.x;
    size_t stride = (size_t)gridDim.x * blockDim.x;
    float m = 0.0f;
    for (; i < n4; i += stride) {
        float4 v = x4[i];
        m = fmaxf(m, fmaxf(fmaxf(fabsf(v.x), fabsf(v.y)), fmaxf(fabsf(v.z), fabsf(v.w))));
    }
    block_amax_atomic(m, slots + t);
}

// ---------- batched quantize of 5 f32 tensors -> bf16-int ----------
struct Quant5Args { const float* p[5]; u16* o[5]; size_t n4[5]; };
__global__ __launch_bounds__(256) void quant5_kernel(Quant5Args a, const unsigned* slots) {
    const int t = blockIdx.y;
    float s = slot_scale(slots + t);
    const float4* x4 = (const float4*)a.p[t];
    ushort4* o4 = (ushort4*)a.o[t];
    const size_t n4 = a.n4[t];
    size_t i = (size_t)blockIdx.x * blockDim.x + threadIdx.x;
    size_t stride = (size_t)gridDim.x * blockDim.x;
    for (; i < n4; i += stride) {
        float4 v = x4[i];
        ushort4 o;
        o.x = qbits(v.x, s); o.y = qbits(v.y, s);
        o.z = qbits(v.z, s); o.w = qbits(v.w, s);
        o4[i] = o;
    }
}

// ---------- plain quantize (attn output) ----------
__global__ __launch_bounds__(256) void quant_kernel(const float* __restrict__ x,
                                                    size_t n4, const unsigned* slot,
                                                    u16* __restrict__ out) {
    float s = slot_scale(slot);
    size_t i = (size_t)blockIdx.x * blockDim.x + threadIdx.x;
    size_t stride = (size_t)gridDim.x * blockDim.x;
    const float4* x4 = (const float4*)x;
    ushort4* o4 = (ushort4*)out;
    for (; i < n4; i += stride) {
        float4 v = x4[i];
        ushort4 o;
        o.x = qbits(v.x, s); o.y = qbits(v.y, s);
        o.z = qbits(v.z, s); o.w = qbits(v.w, s);
        o4[i] = o;
    }
}

// ---------- GEMM body (m97 recipe): 128x128 tile, BK=64, global_load_lds x16 ----------
__device__ __forceinline__ void gemm_body(const u16* __restrict__ A,
                                          const u16* __restrict__ B,
                                          float* __restrict__ C,
                                          int m0, int n0, int N, int K,
                                          float scale, unsigned* out_amax,
                                          u16* Asm, u16* Bsm) {
    const int tid  = threadIdx.x;
    const int lane = tid & 63;
    const int wave = tid >> 6;
    const int wr = (wave >> 1) * 64;
    const int wc = (wave & 1) * 64;
    const int l15 = lane & 15;
    const int l4  = lane >> 4;
    const int srow = lane >> 3;
    const int scol = (lane & 7) * 8;

    f32x4 acc[4][4];
    #pragma unroll
    for (int i = 0; i < 4; ++i)
        #pragma unroll
        for (int j = 0; j < 4; ++j) acc[i][j] = (f32x4){0.f, 0.f, 0.f, 0.f};

    for (int k0 = 0; k0 < K; k0 += 64) {
        __syncthreads();
        #pragma unroll
        for (int c = 0; c < 4; ++c) {
            int seg = wave * 4 + c;
            int gr  = seg * 8 + srow;
            GLD16(&A[(size_t)(m0 + gr) * K + k0 + scol], &Asm[seg * 512]);
            GLD16(&B[(size_t)(n0 + gr) * K + k0 + scol], &Bsm[seg * 512]);
        }
        __syncthreads();
        #pragma unroll
        for (int kk = 0; kk < 2; ++kk) {
            bf16x8 af[4], bfr[4];
            #pragma unroll
            for (int i = 0; i < 4; ++i)
                af[i] = *(const bf16x8*)&Asm[(wr + i * 16 + l15) * 64 + kk * 32 + l4 * 8];
            #pragma unroll
            for (int j = 0; j < 4; ++j)
                bfr[j] = *(const bf16x8*)&Bsm[(wc + j * 16 + l15) * 64 + kk * 32 + l4 * 8];
            #pragma unroll
            for (int i = 0; i < 4; ++i)
                #pragma unroll
                for (int j = 0; j < 4; ++j)
                    acc[i][j] = __builtin_amdgcn_mfma_f32_16x16x32_bf16(af[i], bfr[j], acc[i][j], 0, 0, 0);
        }
    }

    float lm = 0.0f;
    #pragma unroll
    for (int i = 0; i < 4; ++i)
        #pragma unroll
        for (int j = 0; j < 4; ++j)
            #pragma unroll
            for (int r = 0; r < 4; ++r) {
                int row = m0 + wr + i * 16 + l4 * 4 + r;
                int col = n0 + wc + j * 16 + l15;
                float v = acc[i][j][r] * scale;
                C[(size_t)row * N + col] = v;
                lm = fmaxf(lm, fabsf(v));
            }
    if (out_amax) block_amax_atomic(lm, out_amax);
}

__global__ __launch_bounds__(256) void gemm_bt_kernel(const u16* __restrict__ A,
                                                      const u16* __restrict__ B,
                                                      float* __restrict__ C,
                                                      int N, int K,
                                                      const unsigned* __restrict__ sA_slot,
                                                      const unsigned* __restrict__ sB_slot,
                                                      unsigned* out_amax) {
    __shared__ __align__(16) u16 Asm[128 * 64];
    __shared__ __align__(16) u16 Bsm[128 * 64];
    float scale = slot_scale(sA_slot) * slot_scale(sB_slot);
    gemm_body(A, B, C, blockIdx.x * 128, blockIdx.y * 128, N, K, scale, out_amax, Asm, Bsm);
}

__global__ __launch_bounds__(256) void gemm_kv_kernel(const u16* __restrict__ A,
                                                      const u16* __restrict__ Bk,
                                                      const u16* __restrict__ Bv,
                                                      float* __restrict__ Ck,
                                                      float* __restrict__ Cv,
                                                      int K,
                                                      const unsigned* __restrict__ sA_slot,
                                                      const unsigned* __restrict__ sK_slot,
                                                      const unsigned* __restrict__ sV_slot,
                                                      unsigned* v_amax) {
    __shared__ __align__(16) u16 Asm[128 * 64];
    __shared__ __align__(16) u16 Bsm[128 * 64];
    const bool isv = blockIdx.y >= 8;
    const u16* B = isv ? Bv : Bk;
    float*     C = isv ? Cv : Ck;
    float scale = slot_scale(sA_slot) * slot_scale(isv ? sV_slot : sK_slot);
    gemm_body(A, B, C, blockIdx.x * 128, (blockIdx.y & 7) * 128, NKV * HD, K, scale,
              isv ? v_amax : nullptr, Asm, Bsm);
}

// ---------- RMSNorm + RoPE for q (y=0) and k (y=1), in-place, + absmax ----------
__global__ __launch_bounds__(256) void rmsrope2_kernel(float* __restrict__ qx,
                                                       float* __restrict__ kx,
                                                       const float* __restrict__ cosb,
                                                       const float* __restrict__ sinb,
                                                       const float* __restrict__ qw,
                                                       const float* __restrict__ kw,
                                                       unsigned* slots) {
    const int which = blockIdx.y;
    float* x = which ? kx : qx;
    const float* w = which ? kw : qw;
    const int s_shift = which ? 3 : 5;
    const int nrows = which ? (S_LEN * NKV) : (S_LEN * NH);
    unsigned* slot = slots + (which ? 6 : 5);

    const int lane = threadIdx.x & 63;
    const int wid  = threadIdx.x >> 6;
    const float wa = w[lane];
    const float wb = w[lane + 64];
    float lm = 0.0f;
    for (int row = blockIdx.x * 4 + wid; row < nrows; row += gridDim.x * 4) {
        int s = row >> s_shift;
        float* xr = x + (size_t)row * 128;
        float a = xr[lane], b = xr[lane + 64];
        float ss = a * a + b * b;
        #pragma unroll
        for (int o = 32; o; o >>= 1) ss += __shfl_xor(ss, o);
        float inv = 1.0f / sqrtf(ss * (1.0f / 128.0f) + 1e-5f);
        float ya = (a * inv) * wa;
        float yb = (b * inv) * wb;
        const float* cr = cosb + (size_t)s * 128;
        const float* sr = sinb + (size_t)s * 128;
        float o0 = ya * cr[lane]      - yb * sr[lane];
        float o1 = yb * cr[lane + 64] + ya * sr[lane + 64];
        xr[lane] = o0;
        xr[lane + 64] = o1;
        lm = fmaxf(lm, fmaxf(fabsf(o0), fabsf(o1)));
    }
    block_amax_atomic(lm, slot);
}

// ---------- quantize + reorder q and k: (S, nh, D) -> (nh, S, D) ----------
__global__ __launch_bounds__(256) void quant_qk2_kernel(const float* __restrict__ qx,
                                                        const float* __restrict__ kx,
                                                        const unsigned* slots,
                                                        u16* __restrict__ qq,
                                                        u16* __restrict__ kq) {
    int tid = blockIdx.x * 256 + threadIdx.x;
    const int qtot = S_LEN * NH * HD;
    if (tid < qtot) {
        float s = slot_scale(slots + 5);
        int d  = tid & 127;
        int h  = (tid >> 7) & 31;
        int sp = tid >> 12;
        qq[((size_t)h * S_LEN + sp) * 128 + d] = qbits(qx[tid], s);
    } else {
        tid -= qtot;
        float s = slot_scale(slots + 6);
        int d  = tid & 127;
        int h  = (tid >> 7) & 7;
        int sp = tid >> 10;
        kq[((size_t)h * S_LEN + sp) * 128 + d] = qbits(kx[tid], s);
    }
}

// ---------- quantize + transpose V: (S, KV, D) -> (KV, D, S) via LDS tile ----------
__global__ __launch_bounds__(256) void quant_v_kernel(const float* __restrict__ x,
                                                      const unsigned* slot,
                                                      u16* __restrict__ out) {
    __shared__ u16 t16[64][34];
    const float s = slot_scale(slot);
    const int t   = threadIdx.x;
    const int sp0 = blockIdx.x * 64;
    const int d0  = blockIdx.y * 32;
    const int kvh = blockIdx.z;
    const int dl = t & 31;
    const int sb = t >> 5;
    #pragma unroll
    for (int j = 0; j < 8; ++j) {
        int spl = sb + j * 8;
        float v = x[((size_t)(sp0 + spl) * NKV + kvh) * 128 + d0 + dl];
        t16[spl][dl] = qbits(v, s);
    }
    __syncthreads();
    const int dd = t >> 3;
    const int ch = t & 7;
    bf16x8 o;
    #pragma unroll
    for (int j = 0; j < 8; ++j) o[j] = (short)t16[ch * 8 + j][dd];
    *(bf16x8*)&out[((size_t)kvh * 128 + d0 + dd) * S_LEN + sp0 + ch * 8] = o;
}

// ---------- attention: two-pass flash with quantized P ----------
// pass 1 uses SWAPPED mfma(K,Q): each lane holds 4 k-positions of ONE q-row ->
// online softmax is lane-local (no shuffles in loop); butterfly-merge at end.
// 64-row K chunks + register prefetch (async-stage split) in both passes.
__global__ __launch_bounds__(256) void attn_kernel(const u16* __restrict__ Qq,
                                                   const u16* __restrict__ Kq,
                                                   const u16* __restrict__ Vt,
                                                   const unsigned* sq_slot,
                                                   const unsigned* sk_slot,
                                                   const unsigned* sv_slot,
                                                   float* __restrict__ O,
                                                   unsigned* amax_slot) {
    __shared__ __align__(16) u16 Klds[64 * 136];     // 17.4 KB, row stride 272B
    __shared__ __align__(16) u16 Vlds[128 * 72];     // 18.4 KB, row stride 144B
    __shared__ __align__(16) u16 plds[4][16 * 42];   //  5.4 KB per-wave P tiles

    const int tid  = threadIdx.x;
    const int lane = tid & 63;
    const int wave = tid >> 6;
    const int h  = blockIdx.y;
    const int kv = h >> 2;
    const int l15 = lane & 15;
    const int l4  = lane >> 4;
    const size_t kvS = (size_t)kv * S_LEN;

    const float sq = slot_scale(sq_slot);
    const float sk = slot_scale(sk_slot);
    const float sv = slot_scale(sv_slot);
    const float qk_scale = sq * sk * 0.08838834764831845f;
    const float osc = (1.0f / 127.0f) * sv;   // s_p exactly 1/127 (row 0 => max p = 1.0)
    const float NEG = -1e30f;

    float lm = 0.0f;

    #pragma unroll 1
    for (int tpass = 0; tpass < 2; ++tpass) {
        const int qt  = tpass ? (31 - (int)blockIdx.x) : (int)blockIdx.x;
        const int qr0 = qt * 64 + wave * 16;
        const int kb_last = qt * 4 + wave;     // diagonal 16-block for this wave
        const int nchunk  = qt + 1;            // 64-row K chunks

        bf16x8 qf[4];
        {
            const u16* qp = Qq + ((size_t)h * S_LEN + qr0 + l15) * 128 + l4 * 8;
            #pragma unroll
            for (int ks = 0; ks < 4; ++ks) qf[ks] = *(const bf16x8*)(qp + ks * 32);
        }

        // ================= pass 1: lane-local online m,l (swapped mfma) ==========
        float m_l = NEG, l_l = 0.0f;
        bf16x8 kreg[4];
        #pragma unroll
        for (int c = 0; c < 4; ++c) {
            int idx = c * 256 + tid;
            kreg[c] = *(const bf16x8*)&Kq[(kvS + (idx >> 4)) * 128 + (idx & 15) * 8];
        }
        #pragma unroll 1
        for (int kc = 0; kc < nchunk; ++kc) {
            __syncthreads();
            #pragma unroll
            for (int c = 0; c < 4; ++c) {
                int idx = c * 256 + tid;
                *(bf16x8*)&Klds[(idx >> 4) * 136 + (idx & 15) * 8] = kreg[c];
            }
            __syncthreads();
            if (kc + 1 < nchunk) {
                #pragma unroll
                for (int c = 0; c < 4; ++c) {
                    int idx = c * 256 + tid;
                    kreg[c] = *(const bf16x8*)&Kq[(kvS + (kc + 1) * 64 + (idx >> 4)) * 128 + (idx & 15) * 8];
                }
            }
            #pragma unroll
            for (int hb = 0; hb < 4; ++hb) {
                int kb = kc * 4 + hb;
                if (kb > kb_last) continue;          // wave-uniform
                f32x4 sacc = {0.f, 0.f, 0.f, 0.f};
                #pragma unroll
                for (int ks = 0; ks < 4; ++ks) {
                    bf16x8 kf = *(const bf16x8*)&Klds[(hb * 16 + l15) * 136 + ks * 32 + l4 * 8];
                    sacc = __builtin_amdgcn_mfma_f32_16x16x32_bf16(kf, qf[ks], sacc, 0, 0, 0);
                }
                // lane holds scores for q-row = l15 (local), k = kb*16 + l4*4 + r
                const bool diagb = (kb == kb_last);
                float sc[4];
                float bm = NEG;
                #pragma unroll
                for (int r = 0; r < 4; ++r) {
                    float x = sacc[r] * qk_scale;
                    bool msk = diagb && ((l4 * 4 + r) > l15);
                    sc[r] = x;
                    bm = fmaxf(bm, msk ? NEG : x);
                }
                float mn = fmaxf(m_l, bm);
                float corr = __expf(m_l - mn);
                float ps = 0.0f;
                #pragma unroll
                for (int r = 0; r < 4; ++r) {
                    bool msk = diagb && ((l4 * 4 + r) > l15);
                    float p = msk ? 0.0f : __expf(sc[r] - mn);
                    ps += p;
                }
                l_l = l_l * corr + ps;
                m_l = mn;
            }
        }
        // merge 4 lane-groups (butterfly over lanes 16, 32)
        float m2 = fmaxf(m_l, __shfl_xor(m_l, 16));
        float mfin = fmaxf(m2, __shfl_xor(m2, 32));
        float t = l_l * __expf(m_l - mfin);
        t += __shfl_xor(t, 16);
        t += __shfl_xor(t, 32);
        float rl = 127.0f / t;
        // broadcast to standard (q-row = l4*4+r) layout for pass 2
        float mrowB[4], rlB[4];
        #pragma unroll
        for (int r = 0; r < 4; ++r) {
            mrowB[r] = __shfl(mfin, l4 * 4 + r);
            rlB[r]   = __shfl(rl,   l4 * 4 + r);
        }

        // ================= pass 2: quantized P @ V ==============================
        f32x4 oacc[8];
        #pragma unroll
        for (int dt = 0; dt < 8; ++dt) oacc[dt] = (f32x4){0.f, 0.f, 0.f, 0.f};

        bf16x8 vreg[4];
        #pragma unroll
        for (int c = 0; c < 4; ++c) {
            int idx = c * 256 + tid;
            kreg[c] = *(const bf16x8*)&Kq[(kvS + (idx >> 4)) * 128 + (idx & 15) * 8];
            vreg[c] = *(const bf16x8*)&Vt[((size_t)kv * 128 + (idx >> 3)) * S_LEN + (idx & 7) * 8];
        }
        #pragma unroll 1
        for (int kc = 0; kc < nchunk; ++kc) {
            __syncthreads();
            #pragma unroll
            for (int c = 0; c < 4; ++c) {
                int idx = c * 256 + tid;
                *(bf16x8*)&Klds[(idx >> 4) * 136 + (idx & 15) * 8] = kreg[c];
                *(bf16x8*)&Vlds[(idx >> 3) * 72 + (idx & 7) * 8] = vreg[c];
            }
            __syncthreads();
            if (kc + 1 < nchunk) {
                #pragma unroll
                for (int c = 0; c < 4; ++c) {
                    int idx = c * 256 + tid;
                    kreg[c] = *(const bf16x8*)&Kq[(kvS + (kc + 1) * 64 + (idx >> 4)) * 128 + (idx & 15) * 8];
                    vreg[c] = *(const bf16x8*)&Vt[((size_t)kv * 128 + (idx >> 3)) * S_LEN + (kc + 1) * 64 + (idx & 7) * 8];
                }
            }
            #pragma unroll
            for (int hb = 0; hb < 4; ++hb) {
                int kb = kc * 4 + hb;
                u16 pz[4] = {0, 0, 0, 0};
                if (kb <= kb_last) {
                    f32x4 sacc = {0.f, 0.f, 0.f, 0.f};
                    #pragma unroll
                    for (int ks = 0; ks < 4; ++ks) {
                        bf16x8 kf = *(const bf16x8*)&Klds[(hb * 16 + l15) * 136 + ks * 32 + l4 * 8];
                        sacc = __builtin_amdgcn_mfma_f32_16x16x32_bf16(qf[ks], kf, sacc, 0, 0, 0);
                    }
                    const bool diagb = (kb == kb_last);
                    #pragma unroll
                    for (int r = 0; r < 4; ++r) {
                        float x = sacc[r] * qk_scale;
                        float p = __expf(x - mrowB[r]) * rlB[r];
                        float pq = (diagb && (l15 > l4 * 4 + r)) ? 0.0f : rintf(p);
                        pz[r] = (u16)(__float_as_uint(pq) >> 16);
                    }
                }
                #pragma unroll
                for (int r = 0; r < 4; ++r)
                    plds[wave][(l4 * 4 + r) * 42 + (hb & 1) * 16 + l15] = pz[r];
                if (hb & 1) {
                    bf16x8 pf = *(const bf16x8*)&plds[wave][l15 * 42 + l4 * 8];
                    const int cb = (hb >> 1) * 32;
                    #pragma unroll
                    for (int dt = 0; dt < 8; ++dt) {
                        bf16x8 vf = *(const bf16x8*)&Vlds[(dt * 16 + l15) * 72 + cb + l4 * 8];
                        oacc[dt] = __builtin_amdgcn_mfma_f32_16x16x32_bf16(pf, vf, oacc[dt], 0, 0, 0);
                    }
                }
            }
        }

        #pragma unroll
        for (int dt = 0; dt < 8; ++dt)
            #pragma unroll
            for (int r = 0; r < 4; ++r) {
                int qrow = qr0 + l4 * 4 + r;
                float v = oacc[dt][r] * osc;
                O[(size_t)qrow * (NH * 128) + h * 128 + dt * 16 + l15] = v;
                lm = fmaxf(lm, fabsf(v));
            }
    }
    block_amax_atomic(lm, amax_slot);
}

// ---------- host ----------
extern "C" void kernel_launch(void* const* d_in, const int* in_sizes, int n_in,
                              void* d_out, int out_size, void* d_ws, size_t ws_size,
                              hipStream_t stream) {
    const float* hs   = (const float*)d_in[0];
    const float* cosb = (const float*)d_in[1];
    const float* sinb = (const float*)d_in[2];
    const float* Wq   = (const float*)d_in[4];
    const float* Wk   = (const float*)d_in[5];
    const float* Wv   = (const float*)d_in[6];
    const float* Wo   = (const float*)d_in[7];
    const float* qnw  = (const float*)d_in[8];
    const float* knw  = (const float*)d_in[9];
    float* out = (float*)d_out;

    char* ws = (char*)d_ws;
    unsigned* slots = (unsigned*)ws;
    // slots: 0 hs, 1 Wq, 2 Wk, 3 Wv, 4 Wo, 5 q, 6 k, 7 v, 8 attn
    size_t off = 256;
    auto take = [&](size_t bytes) { size_t o = off; off += (bytes + 255) & ~(size_t)255; return o; };
    u16*   hsq  = (u16*)(ws + take((size_t)S_LEN * HIDD * 2));
    u16*   Wqq  = (u16*)(ws + take((size_t)NH * HD * HIDD * 2));
    u16*   Wkq  = (u16*)(ws + take((size_t)NKV * HD * HIDD * 2));
    u16*   Wvq  = (u16*)(ws + take((size_t)NKV * HD * HIDD * 2));
    u16*   Woq  = (u16*)(ws + take((size_t)HIDD * NH * HD * 2));
    float* qf   = (float*)(ws + take((size_t)S_LEN * NH * HD * 4));
    float* kf   = (float*)(ws + take((size_t)S_LEN * NKV * HD * 4));
    float* vf   = (float*)(ws + take((size_t)S_LEN * NKV * HD * 4));
    u16*   qq   = (u16*)(ws + take((size_t)NH * S_LEN * HD * 2));
    u16*   kq   = (u16*)(ws + take((size_t)NKV * S_LEN * HD * 2));
    u16*   vtq  = (u16*)(ws + take((size_t)NKV * HD * S_LEN * 2));
    float* attnf = qf;     // q f32 dead after quant_qk
    u16*   attnq = hsq;    // hs_q dead after the three projections

    hipMemsetAsync(ws, 0, 64, stream);

    const size_t n_hs = (size_t)S_LEN * HIDD;
    const size_t n_wq = (size_t)NH * HD * HIDD;
    const size_t n_wk = (size_t)NKV * HD * HIDD;

    Amax5Args aa;
    aa.p[0] = hs; aa.p[1] = Wq; aa.p[2] = Wk; aa.p[3] = Wv; aa.p[4] = Wo;
    aa.n4[0] = n_hs / 4; aa.n4[1] = n_wq / 4; aa.n4[2] = n_wk / 4;
    aa.n4[3] = n_wk / 4; aa.n4[4] = n_wq / 4;
    absmax5_kernel<<<dim3(512, 5), 256, 0, stream>>>(aa, slots);

    Quant5Args qa;
    qa.p[0] = hs; qa.p[1] = Wq; qa.p[2] = Wk; qa.p[3] = Wv; qa.p[4] = Wo;
    qa.o[0] = hsq; qa.o[1] = Wqq; qa.o[2] = Wkq; qa.o[3] = Wvq; qa.o[4] = Woq;
    qa.n4[0] = n_hs / 4; qa.n4[1] = n_wq / 4; qa.n4[2] = n_wk / 4;
    qa.n4[3] = n_wk / 4; qa.n4[4] = n_wq / 4;
    quant5_kernel<<<dim3(1024, 5), 256, 0, stream>>>(qa, slots);

    gemm_bt_kernel<<<dim3(16, 32), 256, 0, stream>>>(hsq, Wqq, qf, NH * HD, HIDD,
                                                     slots + 0, slots + 1, nullptr);
    gemm_kv_kernel<<<dim3(16, 16), 256, 0, stream>>>(hsq, Wkq, Wvq, kf, vf, HIDD,
                                                     slots + 0, slots + 2, slots + 3, slots + 7);

    rmsrope2_kernel<<<dim3(1024, 2), 256, 0, stream>>>(qf, kf, cosb, sinb, qnw, knw, slots);

    quant_qk2_kernel<<<40960, 256, 0, stream>>>(qf, kf, slots, qq, kq);
    quant_v_kernel<<<dim3(32, 4, 8), 256, 0, stream>>>(vf, slots + 7, vtq);

    attn_kernel<<<dim3(16, NH), 256, 0, stream>>>(qq, kq, vtq,
                                                  slots + 5, slots + 6, slots + 7,
                                                  attnf, slots + 8);

    quant_kernel<<<2048, 256, 0, stream>>>(attnf, n_hs / 4, slots + 8, attnq);
    gemm_bt_kernel<<<dim3(16, 32), 256, 0, stream>>>(attnq, Woq, out, NH * HD, HIDD,
                                                     slots + 8, slots + 4, nullptr);
    (void)in_sizes; (void)n_in; (void)out_size; (void)ws_size;
}

// Round 5
// 388.887 us; speedup vs baseline: 5.8623x; 1.5422x over previous
//
#include <hip/hip_runtime.h>
#include <hip/hip_bf16.h>
#include <math.h>
#include <stdint.h>

// Problem constants
#define S_LEN 2048
#define NH    32
#define NKV   8
#define HD    128
#define HIDD  4096

typedef unsigned short u16;
typedef __attribute__((ext_vector_type(4))) int i32x4;   // 16B = MFMA i8 frag / 4 i32 acc

// async global->LDS, 16B per lane. LDS dest is wave-uniform base + lane*16.
#define GLD16(g, l) __builtin_amdgcn_global_load_lds( \
    (const __attribute__((address_space(1))) void*)(g), \
    (__attribute__((address_space(3))) void*)(l), 16, 0, 0)

// ---------- helpers ----------

__device__ __forceinline__ float slot_scale(const unsigned* slot) {
    return fmaxf(__uint_as_float(*slot), 1e-5f) / 127.0f;
}

// quantize to integer in [-128,127]
__device__ __forceinline__ int qint(float x, float s) {
    float q = rintf(x / s);
    q = fminf(fmaxf(q, -128.0f), 127.0f);
    return (int)q;
}

__device__ __forceinline__ void block_amax_atomic(float m, unsigned* slot) {
    __shared__ float wmax[8];
    const int lane = threadIdx.x & 63;
    const int wid  = threadIdx.x >> 6;
    const int nw   = blockDim.x >> 6;
    #pragma unroll
    for (int o = 32; o; o >>= 1) m = fmaxf(m, __shfl_xor(m, o));
    if (lane == 0) wmax[wid] = m;
    __syncthreads();
    if (threadIdx.x == 0) {
        float bm = wmax[0];
        for (int i = 1; i < nw; ++i) bm = fmaxf(bm, wmax[i]);
        atomicMax(slot, __float_as_uint(bm));
    }
}

// ---------- batched absmax over 5 f32 tensors ----------
struct Amax5Args { const float* p[5]; size_t n4[5]; };
__global__ __launch_bounds__(256) void absmax5_kernel(Amax5Args a, unsigned* slots) {
    const int t = blockIdx.y;
    const float4* x4 = (const float4*)a.p[t];
    const size_t n4 = a.n4[t];
    size_t i = (size_t)blockIdx.x * blockDim.x + threadIdx.x;
    size_t stride = (size_t)gridDim.x * blockDim.x;
    float m = 0.0f;
    for (; i < n4; i += stride) {
        float4 v = x4[i];
        m = fmaxf(m, fmaxf(fmaxf(fabsf(v.x), fabsf(v.y)), fmaxf(fabsf(v.z), fabsf(v.w))));
    }
    block_amax_atomic(m, slots + t);
}

// ---------- batched quantize of 5 f32 tensors -> int8 ----------
struct Quant5Args { const float* p[5]; char* o[5]; size_t n4[5]; };
__global__ __launch_bounds__(256) void quant5_kernel(Quant5Args a, const unsigned* slots) {
    const int t = blockIdx.y;
    float s = slot_scale(slots + t);
    const float4* x4 = (const float4*)a.p[t];
    unsigned* o4 = (unsigned*)a.o[t];
    const size_t n4 = a.n4[t];
    size_t i = (size_t)blockIdx.x * blockDim.x + threadIdx.x;
    size_t stride = (size_t)gridDim.x * blockDim.x;
    for (; i < n4; i += stride) {
        float4 v = x4[i];
        unsigned o = (unsigned)(qint(v.x, s) & 255)
                   | ((unsigned)(qint(v.y, s) & 255) << 8)
                   | ((unsigned)(qint(v.z, s) & 255) << 16)
                   | ((unsigned)(qint(v.w, s) & 255) << 24);
        o4[i] = o;
    }
}

// ---------- plain quantize (attn output) ----------
__global__ __launch_bounds__(256) void quant_kernel(const float* __restrict__ x,
                                                    size_t n4, const unsigned* slot,
                                                    char* __restrict__ out) {
    float s = slot_scale(slot);
    size_t i = (size_t)blockIdx.x * blockDim.x + threadIdx.x;
    size_t stride = (size_t)gridDim.x * blockDim.x;
    const float4* x4 = (const float4*)x;
    unsigned* o4 = (unsigned*)out;
    for (; i < n4; i += stride) {
        float4 v = x4[i];
        unsigned o = (unsigned)(qint(v.x, s) & 255)
                   | ((unsigned)(qint(v.y, s) & 255) << 8)
                   | ((unsigned)(qint(v.z, s) & 255) << 16)
                   | ((unsigned)(qint(v.w, s) & 255) << 24);
        o4[i] = o;
    }
}

// ---------- i8 GEMM body: 128x128 tile, BK=128, global_load_lds x16 ----------
// LDS layout [kk][row][64] (kk = K-half) keeps row stride 64B (8-way max conflict).
__device__ __forceinline__ void gemm_body(const char* __restrict__ A,
                                          const char* __restrict__ B,
                                          float* __restrict__ C,
                                          int m0, int n0, int N, int K,
                                          float scale, unsigned* out_amax,
                                          char* Asm, char* Bsm) {
    const int tid  = threadIdx.x;
    const int lane = tid & 63;
    const int wave = tid >> 6;
    const int wr = (wave >> 1) * 64;
    const int wc = (wave & 1) * 64;
    const int l15 = lane & 15;
    const int l4  = lane >> 4;

    i32x4 acc[4][4];
    #pragma unroll
    for (int i = 0; i < 4; ++i)
        #pragma unroll
        for (int j = 0; j < 4; ++j) acc[i][j] = (i32x4){0, 0, 0, 0};

    for (int k0 = 0; k0 < K; k0 += 128) {
        __syncthreads();
        #pragma unroll
        for (int i = 0; i < 4; ++i) {          // 4 issues/matrix; i = kk*2 + half
            int c2  = i * 256 + tid;           // 16B chunk id (0..1023)
            int kk  = i >> 1;
            int row = (c2 >> 2) & 127;
            int col = (c2 & 3) * 16;
            GLD16(&A[(size_t)(m0 + row) * K + k0 + kk * 64 + col], &Asm[i * 4096 + wave * 1024]);
            GLD16(&B[(size_t)(n0 + row) * K + k0 + kk * 64 + col], &Bsm[i * 4096 + wave * 1024]);
        }
        __syncthreads();
        #pragma unroll
        for (int kk = 0; kk < 2; ++kk) {
            i32x4 af[4], bfr[4];
            #pragma unroll
            for (int i = 0; i < 4; ++i)
                af[i] = *(const i32x4*)&Asm[kk * 8192 + (wr + i * 16 + l15) * 64 + l4 * 16];
            #pragma unroll
            for (int j = 0; j < 4; ++j)
                bfr[j] = *(const i32x4*)&Bsm[kk * 8192 + (wc + j * 16 + l15) * 64 + l4 * 16];
            #pragma unroll
            for (int i = 0; i < 4; ++i)
                #pragma unroll
                for (int j = 0; j < 4; ++j)
                    acc[i][j] = __builtin_amdgcn_mfma_i32_16x16x64_i8(af[i], bfr[j], acc[i][j], 0, 0, 0);
        }
    }

    float lm = 0.0f;
    #pragma unroll
    for (int i = 0; i < 4; ++i)
        #pragma unroll
        for (int j = 0; j < 4; ++j)
            #pragma unroll
            for (int r = 0; r < 4; ++r) {
                int row = m0 + wr + i * 16 + l4 * 4 + r;
                int col = n0 + wc + j * 16 + l15;
                float v = (float)acc[i][j][r] * scale;
                C[(size_t)row * N + col] = v;
                lm = fmaxf(lm, fabsf(v));
            }
    if (out_amax) block_amax_atomic(lm, out_amax);
}

__global__ __launch_bounds__(256) void gemm_bt_kernel(const char* __restrict__ A,
                                                      const char* __restrict__ B,
                                                      float* __restrict__ C,
                                                      int N, int K,
                                                      const unsigned* __restrict__ sA_slot,
                                                      const unsigned* __restrict__ sB_slot,
                                                      unsigned* out_amax) {
    __shared__ __align__(16) char Asm[2 * 128 * 64];
    __shared__ __align__(16) char Bsm[2 * 128 * 64];
    // XCD-aware bijective swizzle: nwg = 16*32 = 512, 512/8 = 64 per XCD
    int bid = blockIdx.y * 16 + blockIdx.x;
    int swz = (bid & 7) * 64 + (bid >> 3);
    float scale = slot_scale(sA_slot) * slot_scale(sB_slot);
    gemm_body(A, B, C, (swz & 15) * 128, (swz >> 4) * 128, N, K, scale, out_amax, Asm, Bsm);
}

__global__ __launch_bounds__(256) void gemm_kv_kernel(const char* __restrict__ A,
                                                      const char* __restrict__ Bk,
                                                      const char* __restrict__ Bv,
                                                      float* __restrict__ Ck,
                                                      float* __restrict__ Cv,
                                                      int K,
                                                      const unsigned* __restrict__ sA_slot,
                                                      const unsigned* __restrict__ sK_slot,
                                                      const unsigned* __restrict__ sV_slot,
                                                      unsigned* v_amax) {
    __shared__ __align__(16) char Asm[2 * 128 * 64];
    __shared__ __align__(16) char Bsm[2 * 128 * 64];
    // nwg = 16*16 = 256, 256/8 = 32 per XCD
    int bid = blockIdx.y * 16 + blockIdx.x;
    int swz = (bid & 7) * 32 + (bid >> 3);
    int sx = swz & 15, sy = swz >> 4;
    const bool isv = sy >= 8;
    const char* B = isv ? Bv : Bk;
    float*      C = isv ? Cv : Ck;
    float scale = slot_scale(sA_slot) * slot_scale(isv ? sV_slot : sK_slot);
    gemm_body(A, B, C, sx * 128, (sy & 7) * 128, NKV * HD, K, scale,
              isv ? v_amax : nullptr, Asm, Bsm);
}

// ---------- RMSNorm + RoPE for q (y=0) and k (y=1), in-place, + absmax ----------
__global__ __launch_bounds__(256) void rmsrope2_kernel(float* __restrict__ qx,
                                                       float* __restrict__ kx,
                                                       const float* __restrict__ cosb,
                                                       const float* __restrict__ sinb,
                                                       const float* __restrict__ qw,
                                                       const float* __restrict__ kw,
                                                       unsigned* slots) {
    const int which = blockIdx.y;
    float* x = which ? kx : qx;
    const float* w = which ? kw : qw;
    const int s_shift = which ? 3 : 5;
    const int nrows = which ? (S_LEN * NKV) : (S_LEN * NH);
    unsigned* slot = slots + (which ? 6 : 5);

    const int lane = threadIdx.x & 63;
    const int wid  = threadIdx.x >> 6;
    const float wa = w[lane];
    const float wb = w[lane + 64];
    float lm = 0.0f;
    for (int row = blockIdx.x * 4 + wid; row < nrows; row += gridDim.x * 4) {
        int s = row >> s_shift;
        float* xr = x + (size_t)row * 128;
        float a = xr[lane], b = xr[lane + 64];
        float ss = a * a + b * b;
        #pragma unroll
        for (int o = 32; o; o >>= 1) ss += __shfl_xor(ss, o);
        float inv = 1.0f / sqrtf(ss * (1.0f / 128.0f) + 1e-5f);
        float ya = (a * inv) * wa;
        float yb = (b * inv) * wb;
        const float* cr = cosb + (size_t)s * 128;
        const float* sr = sinb + (size_t)s * 128;
        float o0 = ya * cr[lane]      - yb * sr[lane];
        float o1 = yb * cr[lane + 64] + ya * sr[lane + 64];
        xr[lane] = o0;
        xr[lane + 64] = o1;
        lm = fmaxf(lm, fmaxf(fabsf(o0), fabsf(o1)));
    }
    block_amax_atomic(lm, slot);
}

// ---------- quantize + reorder q and k: (S, nh, D) -> (nh, S, D) int8 ----------
__global__ __launch_bounds__(256) void quant_qk2_kernel(const float* __restrict__ qx,
                                                        const float* __restrict__ kx,
                                                        const unsigned* slots,
                                                        char* __restrict__ qq,
                                                        char* __restrict__ kq) {
    int tid = blockIdx.x * 256 + threadIdx.x;
    const int qtot = S_LEN * NH * HD;
    if (tid < qtot) {
        float s = slot_scale(slots + 5);
        int d  = tid & 127;
        int h  = (tid >> 7) & 31;
        int sp = tid >> 12;
        qq[((size_t)h * S_LEN + sp) * 128 + d] = (char)qint(qx[tid], s);
    } else {
        tid -= qtot;
        float s = slot_scale(slots + 6);
        int d  = tid & 127;
        int h  = (tid >> 7) & 7;
        int sp = tid >> 10;
        kq[((size_t)h * S_LEN + sp) * 128 + d] = (char)qint(kx[tid], s);
    }
}

// ---------- quantize + transpose V: (S, KV, D) -> (KV, D, S) int8 via LDS tile ----------
__global__ __launch_bounds__(256) void quant_v_kernel(const float* __restrict__ x,
                                                      const unsigned* slot,
                                                      char* __restrict__ out) {
    __shared__ unsigned char t8[64][36];
    const float s = slot_scale(slot);
    const int t   = threadIdx.x;
    const int sp0 = blockIdx.x * 64;
    const int d0  = blockIdx.y * 32;
    const int kvh = blockIdx.z;
    const int dl = t & 31;
    const int sb = t >> 5;
    #pragma unroll
    for (int j = 0; j < 8; ++j) {
        int spl = sb + j * 8;
        float v = x[((size_t)(sp0 + spl) * NKV + kvh) * 128 + d0 + dl];
        t8[spl][dl] = (unsigned char)qint(v, s);
    }
    __syncthreads();
    const int dd = t >> 3;
    const int ch = t & 7;
    unsigned lo = 0, hi = 0;
    #pragma unroll
    for (int j = 0; j < 4; ++j) lo |= (unsigned)t8[ch * 8 + j][dd] << (8 * j);
    #pragma unroll
    for (int j = 0; j < 4; ++j) hi |= (unsigned)t8[ch * 8 + 4 + j][dd] << (8 * j);
    *(uint2*)&out[((size_t)kvh * 128 + d0 + dd) * S_LEN + sp0 + ch * 8] = make_uint2(lo, hi);
}

// ---------- attention: two-pass flash, all-int8 MFMA ----------
// pass 1: swapped mfma(K,Q) -> lane-local online softmax (no shuffles in loop).
// pass 2: QK again + quantized P (int 0..127) @ V in i8, exact i32 accum.
__global__ __launch_bounds__(256) void attn_kernel(const char* __restrict__ Qq,
                                                   const char* __restrict__ Kq,
                                                   const char* __restrict__ Vt,
                                                   const unsigned* sq_slot,
                                                   const unsigned* sk_slot,
                                                   const unsigned* sv_slot,
                                                   float* __restrict__ O,
                                                   unsigned* amax_slot) {
    __shared__ __align__(16) char Klds[64 * 144];    // 9.2 KB, stride 144B (2-way max)
    __shared__ __align__(16) char Vlds[128 * 80];    // 10.2 KB, stride 80B
    __shared__ __align__(16) char plds[4][16 * 80];  // 5.1 KB per-wave P tiles

    const int tid  = threadIdx.x;
    const int lane = tid & 63;
    const int wave = tid >> 6;
    const int h  = blockIdx.y;
    const int kv = h >> 2;
    const int l15 = lane & 15;
    const int l4  = lane >> 4;
    const size_t kvS = (size_t)kv * S_LEN;

    const float sq = slot_scale(sq_slot);
    const float sk = slot_scale(sk_slot);
    const float sv = slot_scale(sv_slot);
    const float qk_scale = sq * sk * 0.08838834764831845f;
    const float osc = (1.0f / 127.0f) * sv;   // s_p exactly 1/127 (row 0 => max p = 1.0)
    const float NEG = -1e30f;

    float lm = 0.0f;

    #pragma unroll 1
    for (int tpass = 0; tpass < 2; ++tpass) {
        const int qt  = tpass ? (31 - (int)blockIdx.x) : (int)blockIdx.x;
        const int qr0 = qt * 64 + wave * 16;
        const int kb_last = qt * 4 + wave;     // diagonal 16-block for this wave
        const int nchunk  = qt + 1;            // 64-row K chunks

        i32x4 qf2[2];
        {
            const char* qp = Qq + ((size_t)h * S_LEN + qr0 + l15) * 128 + l4 * 16;
            qf2[0] = *(const i32x4*)(qp);
            qf2[1] = *(const i32x4*)(qp + 64);
        }

        // ================= pass 1: lane-local online m,l (swapped mfma) ==========
        float m_l = NEG, l_l = 0.0f;
        i32x4 kreg[2];
        #pragma unroll
        for (int c = 0; c < 2; ++c) {
            int idx = c * 256 + tid;
            kreg[c] = *(const i32x4*)&Kq[(kvS + (idx >> 3)) * 128 + (idx & 7) * 16];
        }
        #pragma unroll 1
        for (int kc = 0; kc < nchunk; ++kc) {
            __syncthreads();
            #pragma unroll
            for (int c = 0; c < 2; ++c) {
                int idx = c * 256 + tid;
                *(i32x4*)&Klds[(idx >> 3) * 144 + (idx & 7) * 16] = kreg[c];
            }
            __syncthreads();
            if (kc + 1 < nchunk) {
                #pragma unroll
                for (int c = 0; c < 2; ++c) {
                    int idx = c * 256 + tid;
                    kreg[c] = *(const i32x4*)&Kq[(kvS + (kc + 1) * 64 + (idx >> 3)) * 128 + (idx & 7) * 16];
                }
            }
            #pragma unroll
            for (int hb = 0; hb < 4; ++hb) {
                int kb = kc * 4 + hb;
                if (kb > kb_last) continue;          // wave-uniform
                i32x4 sacc = {0, 0, 0, 0};
                #pragma unroll
                for (int c = 0; c < 2; ++c) {
                    i32x4 kfa = *(const i32x4*)&Klds[(hb * 16 + l15) * 144 + c * 64 + l4 * 16];
                    sacc = __builtin_amdgcn_mfma_i32_16x16x64_i8(kfa, qf2[c], sacc, 0, 0, 0);
                }
                // lane holds scores for q-row = l15, k = kb*16 + l4*4 + r
                const bool diagb = (kb == kb_last);
                float sc[4];
                float bm = NEG;
                #pragma unroll
                for (int r = 0; r < 4; ++r) {
                    float x = (float)sacc[r] * qk_scale;
                    bool msk = diagb && ((l4 * 4 + r) > l15);
                    sc[r] = x;
                    bm = fmaxf(bm, msk ? NEG : x);
                }
                float mn = fmaxf(m_l, bm);
                float corr = __expf(m_l - mn);
                float ps = 0.0f;
                #pragma unroll
                for (int r = 0; r < 4; ++r) {
                    bool msk = diagb && ((l4 * 4 + r) > l15);
                    float p = msk ? 0.0f : __expf(sc[r] - mn);
                    ps += p;
                }
                l_l = l_l * corr + ps;
                m_l = mn;
            }
        }
        // merge 4 lane-groups (butterfly over lanes 16, 32)
        float m2 = fmaxf(m_l, __shfl_xor(m_l, 16));
        float mfin = fmaxf(m2, __shfl_xor(m2, 32));
        float t = l_l * __expf(m_l - mfin);
        t += __shfl_xor(t, 16);
        t += __shfl_xor(t, 32);
        float rl = 127.0f / t;
        float mrowB[4], rlB[4];
        #pragma unroll
        for (int r = 0; r < 4; ++r) {
            mrowB[r] = __shfl(mfin, l4 * 4 + r);
            rlB[r]   = __shfl(rl,   l4 * 4 + r);
        }

        // ================= pass 2: quantized P @ V (i8) =========================
        i32x4 oacc[8];
        #pragma unroll
        for (int dt = 0; dt < 8; ++dt) oacc[dt] = (i32x4){0, 0, 0, 0};

        i32x4 vreg[2];
        #pragma unroll
        for (int c = 0; c < 2; ++c) {
            int idx = c * 256 + tid;
            kreg[c] = *(const i32x4*)&Kq[(kvS + (idx >> 3)) * 128 + (idx & 7) * 16];
            vreg[c] = *(const i32x4*)&Vt[((size_t)kv * 128 + (idx >> 2)) * S_LEN + (idx & 3) * 16];
        }
        #pragma unroll 1
        for (int kc = 0; kc < nchunk; ++kc) {
            __syncthreads();
            #pragma unroll
            for (int c = 0; c < 2; ++c) {
                int idx = c * 256 + tid;
                *(i32x4*)&Klds[(idx >> 3) * 144 + (idx & 7) * 16] = kreg[c];
                *(i32x4*)&Vlds[(idx >> 2) * 80 + (idx & 3) * 16] = vreg[c];
            }
            __syncthreads();
            if (kc + 1 < nchunk) {
                #pragma unroll
                for (int c = 0; c < 2; ++c) {
                    int idx = c * 256 + tid;
                    kreg[c] = *(const i32x4*)&Kq[(kvS + (kc + 1) * 64 + (idx >> 3)) * 128 + (idx & 7) * 16];
                    vreg[c] = *(const i32x4*)&Vt[((size_t)kv * 128 + (idx >> 2)) * S_LEN + (kc + 1) * 64 + (idx & 3) * 16];
                }
            }
            #pragma unroll
            for (int hb = 0; hb < 4; ++hb) {
                int kb = kc * 4 + hb;
                unsigned char pz[4] = {0, 0, 0, 0};
                if (kb <= kb_last) {
                    i32x4 sacc = {0, 0, 0, 0};
                    #pragma unroll
                    for (int c = 0; c < 2; ++c) {
                        i32x4 kfb = *(const i32x4*)&Klds[(hb * 16 + l15) * 144 + c * 64 + l4 * 16];
                        sacc = __builtin_amdgcn_mfma_i32_16x16x64_i8(qf2[c], kfb, sacc, 0, 0, 0);
                    }
                    const bool diagb = (kb == kb_last);
                    #pragma unroll
                    for (int r = 0; r < 4; ++r) {
                        float x = (float)sacc[r] * qk_scale;
                        float p = __expf(x - mrowB[r]) * rlB[r];
                        float pq = (diagb && (l15 > l4 * 4 + r)) ? 0.0f : rintf(p);
                        pz[r] = (unsigned char)(int)pq;
                    }
                }
                #pragma unroll
                for (int r = 0; r < 4; ++r)
                    plds[wave][(l4 * 4 + r) * 80 + hb * 16 + l15] = pz[r];
            }
            // full 64-k P tile ready (same wave) -> one i8 PV pass
            i32x4 pf = *(const i32x4*)&plds[wave][l15 * 80 + l4 * 16];
            #pragma unroll
            for (int dt = 0; dt < 8; ++dt) {
                i32x4 vfb = *(const i32x4*)&Vlds[(dt * 16 + l15) * 80 + l4 * 16];
                oacc[dt] = __builtin_amdgcn_mfma_i32_16x16x64_i8(pf, vfb, oacc[dt], 0, 0, 0);
            }
        }

        #pragma unroll
        for (int dt = 0; dt < 8; ++dt)
            #pragma unroll
            for (int r = 0; r < 4; ++r) {
                int qrow = qr0 + l4 * 4 + r;
                float v = (float)oacc[dt][r] * osc;
                O[(size_t)qrow * (NH * 128) + h * 128 + dt * 16 + l15] = v;
                lm = fmaxf(lm, fabsf(v));
            }
    }
    block_amax_atomic(lm, amax_slot);
}

// ---------- host ----------
extern "C" void kernel_launch(void* const* d_in, const int* in_sizes, int n_in,
                              void* d_out, int out_size, void* d_ws, size_t ws_size,
                              hipStream_t stream) {
    const float* hs   = (const float*)d_in[0];
    const float* cosb = (const float*)d_in[1];
    const float* sinb = (const float*)d_in[2];
    const float* Wq   = (const float*)d_in[4];
    const float* Wk   = (const float*)d_in[5];
    const float* Wv   = (const float*)d_in[6];
    const float* Wo   = (const float*)d_in[7];
    const float* qnw  = (const float*)d_in[8];
    const float* knw  = (const float*)d_in[9];
    float* out = (float*)d_out;

    char* ws = (char*)d_ws;
    unsigned* slots = (unsigned*)ws;
    // slots: 0 hs, 1 Wq, 2 Wk, 3 Wv, 4 Wo, 5 q, 6 k, 7 v, 8 attn
    size_t off = 256;
    auto take = [&](size_t bytes) { size_t o = off; off += (bytes + 255) & ~(size_t)255; return o; };
    char*  hsq  = (char*)(ws + take((size_t)S_LEN * HIDD));        //  8 MB
    char*  Wqq  = (char*)(ws + take((size_t)NH * HD * HIDD));      // 16 MB
    char*  Wkq  = (char*)(ws + take((size_t)NKV * HD * HIDD));     //  4 MB
    char*  Wvq  = (char*)(ws + take((size_t)NKV * HD * HIDD));     //  4 MB
    char*  Woq  = (char*)(ws + take((size_t)HIDD * NH * HD));      // 16 MB
    float* qf   = (float*)(ws + take((size_t)S_LEN * NH * HD * 4));
    float* kf   = (float*)(ws + take((size_t)S_LEN * NKV * HD * 4));
    float* vf   = (float*)(ws + take((size_t)S_LEN * NKV * HD * 4));
    char*  qq   = (char*)(ws + take((size_t)NH * S_LEN * HD));
    char*  kq   = (char*)(ws + take((size_t)NKV * S_LEN * HD));
    char*  vtq  = (char*)(ws + take((size_t)NKV * HD * S_LEN));
    float* attnf = qf;     // q f32 dead after quant_qk
    char*  attnq = hsq;    // hs_q dead after the three projections

    hipMemsetAsync(ws, 0, 64, stream);

    const size_t n_hs = (size_t)S_LEN * HIDD;
    const size_t n_wq = (size_t)NH * HD * HIDD;
    const size_t n_wk = (size_t)NKV * HD * HIDD;

    Amax5Args aa;
    aa.p[0] = hs; aa.p[1] = Wq; aa.p[2] = Wk; aa.p[3] = Wv; aa.p[4] = Wo;
    aa.n4[0] = n_hs / 4; aa.n4[1] = n_wq / 4; aa.n4[2] = n_wk / 4;
    aa.n4[3] = n_wk / 4; aa.n4[4] = n_wq / 4;
    absmax5_kernel<<<dim3(512, 5), 256, 0, stream>>>(aa, slots);

    Quant5Args qa;
    qa.p[0] = hs; qa.p[1] = Wq; qa.p[2] = Wk; qa.p[3] = Wv; qa.p[4] = Wo;
    qa.o[0] = hsq; qa.o[1] = Wqq; qa.o[2] = Wkq; qa.o[3] = Wvq; qa.o[4] = Woq;
    qa.n4[0] = n_hs / 4; qa.n4[1] = n_wq / 4; qa.n4[2] = n_wk / 4;
    qa.n4[3] = n_wk / 4; qa.n4[4] = n_wq / 4;
    quant5_kernel<<<dim3(1024, 5), 256, 0, stream>>>(qa, slots);

    gemm_bt_kernel<<<dim3(16, 32), 256, 0, stream>>>(hsq, Wqq, qf, NH * HD, HIDD,
                                                     slots + 0, slots + 1, nullptr);
    gemm_kv_kernel<<<dim3(16, 16), 256, 0, stream>>>(hsq, Wkq, Wvq, kf, vf, HIDD,
                                                     slots + 0, slots + 2, slots + 3, slots + 7);

    rmsrope2_kernel<<<dim3(1024, 2), 256, 0, stream>>>(qf, kf, cosb, sinb, qnw, knw, slots);

    quant_qk2_kernel<<<40960, 256, 0, stream>>>(qf, kf, slots, qq, kq);
    quant_v_kernel<<<dim3(32, 4, 8), 256, 0, stream>>>(vf, slots + 7, vtq);

    attn_kernel<<<dim3(16, NH), 256, 0, stream>>>(qq, kq, vtq,
                                                  slots + 5, slots + 6, slots + 7,
                                                  attnf, slots + 8);

    quant_kernel<<<2048, 256, 0, stream>>>(attnf, n_hs / 4, slots + 8, attnq);
    gemm_bt_kernel<<<dim3(16, 32), 256, 0, stream>>>(attnq, Woq, out, NH * HD, HIDD,
                                                     slots + 8, slots + 4, nullptr);
    (void)in_sizes; (void)n_in; (void)out_size; (void)ws_size;
}